// Round 2
// baseline (9856.669 us; speedup 1.0000x reference)
//
#include <hip/hip_runtime.h>
#include <hip/hip_bf16.h>

#define NN 50000
#define NE 300000
#define DD 256
#define TE 16

typedef __hip_bfloat16 bf16;

__device__ __forceinline__ float bf2f(bf16 v) { return __bfloat162float(v); }
__device__ __forceinline__ float gelu_f(float v) {
    return 0.5f * v * (1.f + erff(v * 0.70710678118654752f));
}
__device__ __forceinline__ void atomicMaxF(float* addr, float v) {
    if (v >= 0.f) atomicMax((int*)addr, __float_as_int(v));
    else          atomicMin((unsigned int*)addr, __float_as_uint(v));
}

// h = x (f32 copy into d_out, which doubles as the residual stream)
__global__ void cast_x_kernel(const float* __restrict__ x, float* __restrict__ h, int n4) {
    for (int i = blockIdx.x * blockDim.x + threadIdx.x; i < n4; i += gridDim.x * blockDim.x)
        ((float4*)h)[i] = ((const float4*)x)[i];
}

__global__ void fill_kernel(float* __restrict__ p, float v, int n) {
    for (int i = blockIdx.x * blockDim.x + threadIdx.x; i < n; i += gridDim.x * blockDim.x)
        p[i] = v;
}

// one node per block, 64 threads, 4 channels each; f32 in, bf16 out
__global__ __launch_bounds__(64) void ln_kernel(const float* __restrict__ h,
        const float* __restrict__ g, const float* __restrict__ b, bf16* __restrict__ hn) {
    int n = blockIdx.x, t = threadIdx.x;
    float4 v = ((const float4*)(h + (size_t)n * DD))[t];
    float s  = v.x + v.y + v.z + v.w;
    float s2 = v.x * v.x + v.y * v.y + v.z * v.z + v.w * v.w;
    #pragma unroll
    for (int off = 32; off; off >>= 1) {
        s  += __shfl_down(s, off);
        s2 += __shfl_down(s2, off);
    }
    s = __shfl(s, 0); s2 = __shfl(s2, 0);
    float mu  = s * (1.f / DD);
    float var = s2 * (1.f / DD) - mu * mu;
    float rs  = rsqrtf(var + 1e-5f);
    float vv[4] = {v.x, v.y, v.z, v.w};
    ushort4 pk;
    unsigned short* pku = (unsigned short*)&pk;
    #pragma unroll
    for (int j = 0; j < 4; ++j) {
        int c = t * 4 + j;
        float o = (vv[j] - mu) * rs * g[c] + b[c];
        bf16 ov = __float2bfloat16(o);
        pku[j] = *reinterpret_cast<unsigned short*>(&ov);
    }
    ((ushort4*)(hn + (size_t)n * DD))[t] = pk;
}

// xjt[e][o] = gelu( concat(hn[src[e]], rel[e]) @ Wt[kg[e]] + bt[kg[e]] )
__global__ __launch_bounds__(256) void transfer_kernel(
        const bf16* __restrict__ hn, const float* __restrict__ rel,
        const int* __restrict__ src, const int* __restrict__ kg,
        const float* __restrict__ Wt, const float* __restrict__ bt,
        bf16* __restrict__ xjt) {
    __shared__ float xs[TE][512];   // 32 KB
    __shared__ int skg[TE];
    int t = threadIdx.x;
    int e0 = blockIdx.x * TE;
    #pragma unroll
    for (int i = 0; i < 32; ++i) {
        int flat = i * 256 + t;
        int e = flat >> 9, c = flat & 511;
        int ge = e0 + e;
        float v;
        if (c < 256) v = bf2f(hn[(size_t)src[ge] * DD + c]);
        else         v = rel[(size_t)ge * DD + (c - 256)];
        xs[e][c] = v;
    }
    if (t < TE) skg[t] = kg[e0 + t];
    __syncthreads();
    int kge[TE];
    #pragma unroll
    for (int e = 0; e < TE; ++e) kge[e] = skg[e];
    float a0[TE], a1[TE];
    #pragma unroll
    for (int e = 0; e < TE; ++e) { a0[e] = 0.f; a1[e] = 0.f; }
    const float* W0 = Wt;
    const float* W1 = Wt + 512 * DD;
    int o = t;
    for (int d = 0; d < 512; d += 4) {
        float w0[4], w1[4];
        #pragma unroll
        for (int j = 0; j < 4; ++j) {
            w0[j] = W0[(size_t)(d + j) * DD + o];
            w1[j] = W1[(size_t)(d + j) * DD + o];
        }
        #pragma unroll
        for (int e = 0; e < TE; ++e) {
            float4 xv = *(const float4*)&xs[e][d];
            a0[e] = fmaf(xv.x, w0[0], a0[e]); a1[e] = fmaf(xv.x, w1[0], a1[e]);
            a0[e] = fmaf(xv.y, w0[1], a0[e]); a1[e] = fmaf(xv.y, w1[1], a1[e]);
            a0[e] = fmaf(xv.z, w0[2], a0[e]); a1[e] = fmaf(xv.z, w1[2], a1[e]);
            a0[e] = fmaf(xv.w, w0[3], a0[e]); a1[e] = fmaf(xv.w, w1[3], a1[e]);
        }
    }
    float b0 = bt[o], b1 = bt[DD + o];
    #pragma unroll
    for (int e = 0; e < TE; ++e) {
        float v = kge[e] ? (a1[e] + b1) : (a0[e] + b0);
        xjt[(size_t)(e0 + e) * DD + o] = __float2bfloat16(gelu_f(v));
    }
}

// att[e][h] = (q[e] . k[e])_head_h * beta[e] / 8 ; head h == wave h (o = t)
__global__ __launch_bounds__(256) void qkatt_kernel(
        const bf16* __restrict__ hn, const bf16* __restrict__ xjt,
        const int* __restrict__ dst, const int* __restrict__ kgd, const int* __restrict__ kgs,
        const float* __restrict__ Wq, const float* __restrict__ bq,
        const float* __restrict__ Wk, const float* __restrict__ bk,
        const float* __restrict__ beta, float* __restrict__ att) {
    __shared__ float xi[TE][DD];  // 16 KB
    __shared__ float xj[TE][DD];  // 16 KB
    __shared__ int skgd[TE], skgs[TE];
    int t = threadIdx.x, e0 = blockIdx.x * TE;
    #pragma unroll
    for (int i = 0; i < 16; ++i) {
        int flat = i * 256 + t;
        int e = flat >> 8, c = flat & 255;
        int ge = e0 + e;
        xi[e][c] = bf2f(hn[(size_t)dst[ge] * DD + c]);
        xj[e][c] = bf2f(xjt[(size_t)ge * DD + c]);
    }
    if (t < TE) { skgd[t] = kgd[e0 + t]; skgs[t] = kgs[e0 + t]; }
    __syncthreads();
    int o = t;
    float a0[TE], a1[TE];
    // ---- q ----
    #pragma unroll
    for (int e = 0; e < TE; ++e) { a0[e] = 0.f; a1[e] = 0.f; }
    {
        const float* Q0 = Wq;
        const float* Q1 = Wq + DD * DD;
        for (int d = 0; d < DD; d += 4) {
            float w0[4], w1[4];
            #pragma unroll
            for (int j = 0; j < 4; ++j) {
                w0[j] = Q0[(size_t)(d + j) * DD + o];
                w1[j] = Q1[(size_t)(d + j) * DD + o];
            }
            #pragma unroll
            for (int e = 0; e < TE; ++e) {
                float4 xv = *(const float4*)&xi[e][d];
                a0[e] = fmaf(xv.x, w0[0], a0[e]); a1[e] = fmaf(xv.x, w1[0], a1[e]);
                a0[e] = fmaf(xv.y, w0[1], a0[e]); a1[e] = fmaf(xv.y, w1[1], a1[e]);
                a0[e] = fmaf(xv.z, w0[2], a0[e]); a1[e] = fmaf(xv.z, w1[2], a1[e]);
                a0[e] = fmaf(xv.w, w0[3], a0[e]); a1[e] = fmaf(xv.w, w1[3], a1[e]);
            }
        }
    }
    float qv[TE];
    {
        float b0 = bq[o], b1 = bq[DD + o];
        #pragma unroll
        for (int e = 0; e < TE; ++e) qv[e] = skgd[e] ? (a1[e] + b1) : (a0[e] + b0);
    }
    // ---- k ----
    #pragma unroll
    for (int e = 0; e < TE; ++e) { a0[e] = 0.f; a1[e] = 0.f; }
    {
        const float* K0 = Wk;
        const float* K1 = Wk + DD * DD;
        for (int d = 0; d < DD; d += 4) {
            float w0[4], w1[4];
            #pragma unroll
            for (int j = 0; j < 4; ++j) {
                w0[j] = K0[(size_t)(d + j) * DD + o];
                w1[j] = K1[(size_t)(d + j) * DD + o];
            }
            #pragma unroll
            for (int e = 0; e < TE; ++e) {
                float4 xv = *(const float4*)&xj[e][d];
                a0[e] = fmaf(xv.x, w0[0], a0[e]); a1[e] = fmaf(xv.x, w1[0], a1[e]);
                a0[e] = fmaf(xv.y, w0[1], a0[e]); a1[e] = fmaf(xv.y, w1[1], a1[e]);
                a0[e] = fmaf(xv.z, w0[2], a0[e]); a1[e] = fmaf(xv.z, w1[2], a1[e]);
                a0[e] = fmaf(xv.w, w0[3], a0[e]); a1[e] = fmaf(xv.w, w1[3], a1[e]);
            }
        }
    }
    float p[TE];
    {
        float b0 = bk[o], b1 = bk[DD + o];
        #pragma unroll
        for (int e = 0; e < TE; ++e) {
            float kv = skgs[e] ? (a1[e] + b1) : (a0[e] + b0);
            p[e] = qv[e] * kv;
        }
    }
    // per-wave reduce over 64 lanes (= the 64 channels of head h = t>>6)
    #pragma unroll
    for (int off = 1; off < 64; off <<= 1) {
        #pragma unroll
        for (int e = 0; e < TE; ++e) p[e] += __shfl_xor(p[e], off);
    }
    if ((t & 63) == 0) {
        int h = t >> 6;
        #pragma unroll
        for (int e = 0; e < TE; ++e)
            att[(size_t)(e0 + e) * 4 + h] = p[e] * beta[e0 + e] * 0.125f;
    }
}

__global__ void segmax_kernel(const float* __restrict__ att, const int* __restrict__ dst,
                              float* __restrict__ m) {
    int i = blockIdx.x * blockDim.x + threadIdx.x;
    if (i >= NE * 4) return;
    int e = i >> 2, h = i & 3;
    atomicMaxF(m + (size_t)dst[e] * 4 + h, att[i]);
}

__global__ void expsum_kernel(float* __restrict__ att, const int* __restrict__ dst,
                              const float* __restrict__ m, float* __restrict__ denom) {
    int i = blockIdx.x * blockDim.x + threadIdx.x;
    if (i >= NE * 4) return;
    int e = i >> 2, h = i & 3;
    float v = expf(att[i] - m[(size_t)dst[e] * 4 + h]);
    att[i] = v;
    atomicAdd(denom + (size_t)dst[e] * 4 + h, v);
}

__global__ __launch_bounds__(256) void scatter_kernel(const float* __restrict__ ev,
        const float* __restrict__ denom, const bf16* __restrict__ xjt,
        const int* __restrict__ dst, float* __restrict__ aggr) {
    int e = blockIdx.x, t = threadIdx.x;
    int de = dst[e];
    int h = t >> 6;
    float a = ev[(size_t)e * 4 + h] / (denom[(size_t)de * 4 + h] + 1e-16f);
    float val = a * bf2f(xjt[(size_t)e * DD + t]);
    atomicAdd(aggr + (size_t)de * DD + t, val);
}

__global__ void finalize_kernel(float* __restrict__ h, const float* __restrict__ aggr, int n) {
    for (int i = blockIdx.x * blockDim.x + threadIdx.x; i < n; i += gridDim.x * blockDim.x)
        h[i] = h[i] + gelu_f(aggr[i]);
}

extern "C" void kernel_launch(void* const* d_in, const int* in_sizes, int n_in,
                              void* d_out, int out_size, void* d_ws, size_t ws_size,
                              hipStream_t stream) {
    const float* x    = (const float*)d_in[0];
    const int*   ei   = (const int*)d_in[1];
    const int*   ekg  = (const int*)d_in[2];
    const float* beta = (const float*)d_in[3];
    const float* rel  = (const float*)d_in[4];
    const float* ln_g = (const float*)d_in[5];
    const float* ln_b = (const float*)d_in[6];
    const float* Wt   = (const float*)d_in[7];
    const float* bt   = (const float*)d_in[8];
    const float* Wq   = (const float*)d_in[9];
    const float* bq   = (const float*)d_in[10];
    const float* Wk   = (const float*)d_in[11];
    const float* bk   = (const float*)d_in[12];

    float* h = (float*)d_out;   // residual stream lives in d_out (f32)

    const int* srcp = ei;
    const int* dstp = ei + NE;
    const int* kgs  = ekg;
    const int* kgd  = ekg + NE;

    char* w = (char*)d_ws;
    float* aggr  = (float*)w; w += (size_t)NN * DD * 4;   // 51.2 MB
    float* att   = (float*)w; w += (size_t)NE * 4 * 4;    //  4.8 MB
    float* m_buf = (float*)w; w += (size_t)NN * 4 * 4;    //  0.8 MB
    float* denom = (float*)w; w += (size_t)NN * 4 * 4;    //  0.8 MB
    bf16*  hn    = (bf16*)w;  w += (size_t)NN * DD * 2;   // 25.6 MB
    bf16*  xjt   = (bf16*)w;  w += (size_t)NE * DD * 2;   // 153.6 MB

    cast_x_kernel<<<2048, 256, 0, stream>>>(x, h, NN * DD / 4);
    for (int l = 0; l < 2; ++l) {
        ln_kernel<<<NN, 64, 0, stream>>>(h, ln_g + l * DD, ln_b + l * DD, hn);
        transfer_kernel<<<NE / TE, 256, 0, stream>>>(hn, rel, srcp, kgs,
                Wt + (size_t)l * 2 * 512 * DD, bt + (size_t)l * 2 * DD, xjt);
        qkatt_kernel<<<NE / TE, 256, 0, stream>>>(hn, xjt, dstp, kgd, kgs,
                Wq + (size_t)l * 2 * DD * DD, bq + (size_t)l * 2 * DD,
                Wk + (size_t)l * 2 * DD * DD, bk + (size_t)l * 2 * DD, beta, att);
        fill_kernel<<<256, 256, 0, stream>>>(m_buf, -1e30f, NN * 4);
        fill_kernel<<<256, 256, 0, stream>>>(denom, 0.f, NN * 4);
        fill_kernel<<<2048, 256, 0, stream>>>(aggr, 0.f, NN * DD);
        segmax_kernel<<<(NE * 4 + 255) / 256, 256, 0, stream>>>(att, dstp, m_buf);
        expsum_kernel<<<(NE * 4 + 255) / 256, 256, 0, stream>>>(att, dstp, m_buf, denom);
        scatter_kernel<<<NE, 256, 0, stream>>>(att, denom, xjt, dstp, aggr);
        finalize_kernel<<<2048, 256, 0, stream>>>(h, aggr, NN * DD);
    }
}

// Round 3
// 2291.938 us; speedup vs baseline: 4.3006x; 4.3006x over previous
//
#include <hip/hip_runtime.h>
#include <hip/hip_bf16.h>

#define NN 50000
#define NE 300000
#define DD 256

typedef __hip_bfloat16 bf16;
typedef __attribute__((ext_vector_type(8))) short bf16x8;
typedef __attribute__((ext_vector_type(4))) float f32x4;

__device__ __forceinline__ float bf2f(bf16 v) { return __bfloat162float(v); }
__device__ __forceinline__ unsigned short f2b(float v) {
    bf16 t = __float2bfloat16(v);
    return *reinterpret_cast<unsigned short*>(&t);
}
__device__ __forceinline__ float b2f_bits(unsigned short u) {
    return __uint_as_float(((unsigned)u) << 16);
}
__device__ __forceinline__ float gelu_f(float v) {
    return 0.5f * v * (1.f + erff(v * 0.70710678118654752f));
}
__device__ __forceinline__ void atomicMaxF(float* addr, float v) {
    if (v >= 0.f) atomicMax((int*)addr, __float_as_int(v));
    else          atomicMin((unsigned int*)addr, __float_as_uint(v));
}

// ---------------- prep kernels ----------------
__global__ void cast_x_kernel(const float* __restrict__ x, float* __restrict__ h, int n4) {
    for (int i = blockIdx.x * blockDim.x + threadIdx.x; i < n4; i += gridDim.x * blockDim.x)
        ((float4*)h)[i] = ((const float4*)x)[i];
}

__global__ void f2b_vec_kernel(const float* __restrict__ in, ushort* __restrict__ out, long n4) {
    long i0 = (long)blockIdx.x * blockDim.x + threadIdx.x;
    long stride = (long)gridDim.x * blockDim.x;
    for (long i = i0; i < n4; i += stride) {
        float4 v = ((const float4*)in)[i];
        ushort4 o;
        o.x = f2b(v.x); o.y = f2b(v.y); o.z = f2b(v.z); o.w = f2b(v.w);
        ((ushort4*)out)[i] = o;
    }
}

// out[s][o][d] = bf16(in[s][d][o]), dout = 256, din = 1<<shift
__global__ void transpose_w_kernel(const float* __restrict__ in, ushort* __restrict__ out,
                                   int shift, long total) {
    long i0 = (long)blockIdx.x * blockDim.x + threadIdx.x;
    long stride = (long)gridDim.x * blockDim.x;
    long dmask = ((long)1 << shift) - 1;
    for (long i = i0; i < total; i += stride) {
        long d = i & dmask;
        long rest = i >> shift;
        long o = rest & 255;
        long s = rest >> 8;
        out[i] = f2b(in[((s << shift) + d) * 256 + o]);
    }
}

__global__ void fill_kernel(float* __restrict__ p, float v, int n) {
    for (int i = blockIdx.x * blockDim.x + threadIdx.x; i < n; i += gridDim.x * blockDim.x)
        p[i] = v;
}

// ---------------- layernorm ----------------
__global__ __launch_bounds__(64) void ln_kernel(const float* __restrict__ h,
        const float* __restrict__ g, const float* __restrict__ b, bf16* __restrict__ hn) {
    int n = blockIdx.x, t = threadIdx.x;
    float4 v = ((const float4*)(h + (size_t)n * DD))[t];
    float s  = v.x + v.y + v.z + v.w;
    float s2 = v.x * v.x + v.y * v.y + v.z * v.z + v.w * v.w;
    #pragma unroll
    for (int off = 32; off; off >>= 1) {
        s  += __shfl_down(s, off);
        s2 += __shfl_down(s2, off);
    }
    s = __shfl(s, 0); s2 = __shfl(s2, 0);
    float mu  = s * (1.f / DD);
    float var = s2 * (1.f / DD) - mu * mu;
    float rs  = rsqrtf(var + 1e-5f);
    float vv[4] = {v.x, v.y, v.z, v.w};
    ushort4 pk;
    unsigned short* pku = (unsigned short*)&pk;
    #pragma unroll
    for (int j = 0; j < 4; ++j) {
        int c = t * 4 + j;
        pku[j] = f2b((vv[j] - mu) * rs * g[c] + b[c]);
    }
    ((ushort4*)(hn + (size_t)n * DD))[t] = pk;
}

// ---------------- transfer: xjt = gelu(concat(hn[src],rel) @ Wt[kg] + bt[kg]) ----------------
// MFMA: A = WtT[br][o][k] (M=outputs), B = X[e][k] (N=edges), D[o][e]
__global__ __launch_bounds__(512) void transfer_mfma(
        const bf16* __restrict__ hn, const ushort* __restrict__ relb,
        const int* __restrict__ src, const int* __restrict__ kg,
        const ushort* __restrict__ WtT, const float* __restrict__ bt,
        bf16* __restrict__ xjt) {
    __shared__ uint4 xs[64 * 65];       // 64 edge rows x 1040B (512 bf16 + pad)
    __shared__ float bts[2][256];
    __shared__ int skg[64];
    int t = threadIdx.x;
    int e0 = blockIdx.x * 64;
    if (t < 256) { bts[0][t] = bt[t]; bts[1][t] = bt[256 + t]; }
    else if (t < 320) {
        int r = t - 256;
        int ge = e0 + r; if (ge >= NE) ge = NE - 1;
        skg[r] = kg[ge];
    }
    const uint4* hn4 = (const uint4*)hn;    // 32 chunks / row
    const uint4* rl4 = (const uint4*)relb;
    #pragma unroll
    for (int i = 0; i < 8; ++i) {
        int flat = i * 512 + t;
        int r = flat >> 6, c = flat & 63;
        int ge = e0 + r; if (ge >= NE) ge = NE - 1;
        uint4 v;
        if (c < 32) v = hn4[(size_t)src[ge] * 32 + c];
        else        v = rl4[(size_t)ge * 32 + (c - 32)];
        xs[r * 65 + c] = v;
    }
    __syncthreads();
    int wave = t >> 6, lane = t & 63;
    int lr = lane & 15, lg = lane >> 4;
    f32x4 acc[2][2][4];
    #pragma unroll
    for (int b = 0; b < 2; ++b)
        #pragma unroll
        for (int m = 0; m < 2; ++m)
            #pragma unroll
            for (int n = 0; n < 4; ++n) acc[b][m][n] = (f32x4){0.f, 0.f, 0.f, 0.f};
    const char* xsb = (const char*)xs;
    for (int kk = 0; kk < 16; ++kk) {
        bf16x8 bfr[4];
        #pragma unroll
        for (int n = 0; n < 4; ++n)
            bfr[n] = *(const bf16x8*)(xsb + (n * 16 + lr) * 1040 + kk * 64 + lg * 16);
        #pragma unroll
        for (int m = 0; m < 2; ++m) {
            int o = wave * 32 + m * 16 + lr;
            const ushort* wp = WtT + (size_t)o * 512 + kk * 32 + lg * 8;
            bf16x8 a0 = *(const bf16x8*)wp;
            bf16x8 a1 = *(const bf16x8*)(wp + 131072);   // +256*512
            #pragma unroll
            for (int n = 0; n < 4; ++n) {
                acc[0][m][n] = __builtin_amdgcn_mfma_f32_16x16x32_bf16(a0, bfr[n], acc[0][m][n], 0, 0, 0);
                acc[1][m][n] = __builtin_amdgcn_mfma_f32_16x16x32_bf16(a1, bfr[n], acc[1][m][n], 0, 0, 0);
            }
        }
    }
    __syncthreads();
    // epilogue: select branch by kg[e], add bias, gelu, pack bf16 into LDS rows of 528B
    char* xob = (char*)xs;
    #pragma unroll
    for (int n = 0; n < 4; ++n) {
        int e = n * 16 + lr;
        int kge = skg[e];
        #pragma unroll
        for (int m = 0; m < 2; ++m) {
            int ob = wave * 32 + m * 16 + lg * 4;
            f32x4 a = kge ? acc[1][m][n] : acc[0][m][n];
            ushort4 pk;
            unsigned short* pu = (unsigned short*)&pk;
            #pragma unroll
            for (int r = 0; r < 4; ++r) {
                float bb = kge ? bts[1][ob + r] : bts[0][ob + r];
                pu[r] = f2b(gelu_f(a[r] + bb));
            }
            *(ushort4*)(xob + e * 528 + ob * 2) = pk;
        }
    }
    __syncthreads();
    const uint4* xo4 = (const uint4*)xs;
    uint4* xjv = (uint4*)xjt;
    #pragma unroll
    for (int i = 0; i < 4; ++i) {
        int flat = i * 512 + t;
        int r = flat >> 5, c = flat & 31;
        int ge = e0 + r;
        if (ge < NE) xjv[(size_t)ge * 32 + c] = xo4[r * 33 + c];
    }
}

// ---------------- qkatt: att[e][h] = (Wq[kgd]hn[dst] + bq) . (Wk[kgs]xjt + bk) * beta/8 ----------------
__global__ __launch_bounds__(512) void qkatt_mfma(
        const bf16* __restrict__ hn, const bf16* __restrict__ xjt,
        const int* __restrict__ dst, const int* __restrict__ kgd, const int* __restrict__ kgs,
        const ushort* __restrict__ WqT, const float* __restrict__ bq,
        const ushort* __restrict__ WkT, const float* __restrict__ bk,
        const float* __restrict__ beta, float* __restrict__ att) {
    __shared__ uint4 xi4[64 * 33];   // hn[dst] rows, 528B stride
    __shared__ uint4 xj4[64 * 33];   // xjt rows; reused as k-value buffer
    __shared__ float bqs[2][256], bks[2][256];
    __shared__ float patt[8][64];
    __shared__ int sgd[64], sgs[64];
    int t = threadIdx.x;
    int e0 = blockIdx.x * 64;
    if (t < 256) {
        bqs[0][t] = bq[t]; bqs[1][t] = bq[256 + t];
        bks[0][t] = bk[t]; bks[1][t] = bk[256 + t];
    } else if (t < 320) {
        int r = t - 256;
        int ge = e0 + r; if (ge >= NE) ge = NE - 1;
        sgd[r] = kgd[ge]; sgs[r] = kgs[ge];
    }
    const uint4* hnv = (const uint4*)hn;
    const uint4* xjv = (const uint4*)xjt;
    #pragma unroll
    for (int i = 0; i < 4; ++i) {
        int flat = i * 512 + t;
        int r = flat >> 5, c = flat & 31;
        int ge = e0 + r; if (ge >= NE) ge = NE - 1;
        xi4[r * 33 + c] = hnv[(size_t)dst[ge] * 32 + c];
        xj4[r * 33 + c] = xjv[(size_t)ge * 32 + c];
    }
    __syncthreads();
    int wave = t >> 6, lane = t & 63;
    int lr = lane & 15, lg = lane >> 4;
    // ---- k-pass ----
    f32x4 kacc[2][2][4];
    #pragma unroll
    for (int b = 0; b < 2; ++b)
        #pragma unroll
        for (int m = 0; m < 2; ++m)
            #pragma unroll
            for (int n = 0; n < 4; ++n) kacc[b][m][n] = (f32x4){0.f, 0.f, 0.f, 0.f};
    const char* xjb = (const char*)xj4;
    for (int kk = 0; kk < 8; ++kk) {
        bf16x8 bfr[4];
        #pragma unroll
        for (int n = 0; n < 4; ++n)
            bfr[n] = *(const bf16x8*)(xjb + (n * 16 + lr) * 528 + kk * 64 + lg * 16);
        #pragma unroll
        for (int m = 0; m < 2; ++m) {
            int o = wave * 32 + m * 16 + lr;
            const ushort* wp = WkT + (size_t)o * 256 + kk * 32 + lg * 8;
            bf16x8 a0 = *(const bf16x8*)wp;
            bf16x8 a1 = *(const bf16x8*)(wp + 65536);   // +256*256
            #pragma unroll
            for (int n = 0; n < 4; ++n) {
                kacc[0][m][n] = __builtin_amdgcn_mfma_f32_16x16x32_bf16(a0, bfr[n], kacc[0][m][n], 0, 0, 0);
                kacc[1][m][n] = __builtin_amdgcn_mfma_f32_16x16x32_bf16(a1, bfr[n], kacc[1][m][n], 0, 0, 0);
            }
        }
    }
    __syncthreads();   // everyone done reading xj4
    // write selected k values (bf16) into xj4 area; wave-local rows/cols
    char* kb = (char*)xj4;
    #pragma unroll
    for (int n = 0; n < 4; ++n) {
        int e = n * 16 + lr;
        int kge = sgs[e];
        #pragma unroll
        for (int m = 0; m < 2; ++m) {
            int ob = wave * 32 + m * 16 + lg * 4;
            f32x4 a = kge ? kacc[1][m][n] : kacc[0][m][n];
            ushort4 pk;
            unsigned short* pu = (unsigned short*)&pk;
            #pragma unroll
            for (int r = 0; r < 4; ++r) {
                float bb = kge ? bks[1][ob + r] : bks[0][ob + r];
                pu[r] = f2b(a[r] + bb);
            }
            *(ushort4*)(kb + e * 528 + ob * 2) = pk;
        }
    }
    // ---- q-pass ----
    f32x4 qacc[2][2][4];
    #pragma unroll
    for (int b = 0; b < 2; ++b)
        #pragma unroll
        for (int m = 0; m < 2; ++m)
            #pragma unroll
            for (int n = 0; n < 4; ++n) qacc[b][m][n] = (f32x4){0.f, 0.f, 0.f, 0.f};
    const char* xib = (const char*)xi4;
    for (int kk = 0; kk < 8; ++kk) {
        bf16x8 bfr[4];
        #pragma unroll
        for (int n = 0; n < 4; ++n)
            bfr[n] = *(const bf16x8*)(xib + (n * 16 + lr) * 528 + kk * 64 + lg * 16);
        #pragma unroll
        for (int m = 0; m < 2; ++m) {
            int o = wave * 32 + m * 16 + lr;
            const ushort* wp = WqT + (size_t)o * 256 + kk * 32 + lg * 8;
            bf16x8 a0 = *(const bf16x8*)wp;
            bf16x8 a1 = *(const bf16x8*)(wp + 65536);
            #pragma unroll
            for (int n = 0; n < 4; ++n) {
                qacc[0][m][n] = __builtin_amdgcn_mfma_f32_16x16x32_bf16(a0, bfr[n], qacc[0][m][n], 0, 0, 0);
                qacc[1][m][n] = __builtin_amdgcn_mfma_f32_16x16x32_bf16(a1, bfr[n], qacc[1][m][n], 0, 0, 0);
            }
        }
    }
    // ---- per-head dot: q[e][o]*k[e][o], sum over this wave's 32 o's ----
    float p[4] = {0.f, 0.f, 0.f, 0.f};
    #pragma unroll
    for (int n = 0; n < 4; ++n) {
        int e = n * 16 + lr;
        int kgq = sgd[e];
        #pragma unroll
        for (int m = 0; m < 2; ++m) {
            int ob = wave * 32 + m * 16 + lg * 4;
            f32x4 a = kgq ? qacc[1][m][n] : qacc[0][m][n];
            ushort4 kv = *(const ushort4*)(kb + e * 528 + ob * 2);
            unsigned short* ku = (unsigned short*)&kv;
            #pragma unroll
            for (int r = 0; r < 4; ++r) {
                float qv = a[r] + (kgq ? bqs[1][ob + r] : bqs[0][ob + r]);
                p[n] = fmaf(qv, b2f_bits(ku[r]), p[n]);
            }
        }
    }
    #pragma unroll
    for (int n = 0; n < 4; ++n) {
        p[n] += __shfl_xor(p[n], 16);
        p[n] += __shfl_xor(p[n], 32);
    }
    if (lane < 16) {
        #pragma unroll
        for (int n = 0; n < 4; ++n) patt[wave][n * 16 + lr] = p[n];
    }
    __syncthreads();
    if (t < 256) {
        int e = t & 63, h = t >> 6;
        int ge = e0 + e;
        if (ge < NE)
            att[(size_t)ge * 4 + h] = (patt[2 * h][e] + patt[2 * h + 1][e]) * beta[ge] * 0.125f;
    }
}

// ---------------- softmax / aggregate ----------------
__global__ void segmax_kernel(const float* __restrict__ att, const int* __restrict__ dst,
                              float* __restrict__ m) {
    int i = blockIdx.x * blockDim.x + threadIdx.x;
    if (i >= NE * 4) return;
    int e = i >> 2, h = i & 3;
    atomicMaxF(m + (size_t)dst[e] * 4 + h, att[i]);
}

__global__ void expsum_kernel(float* __restrict__ att, const int* __restrict__ dst,
                              const float* __restrict__ m, float* __restrict__ denom) {
    int i = blockIdx.x * blockDim.x + threadIdx.x;
    if (i >= NE * 4) return;
    int e = i >> 2, h = i & 3;
    float v = expf(att[i] - m[(size_t)dst[e] * 4 + h]);
    att[i] = v;
    atomicAdd(denom + (size_t)dst[e] * 4 + h, v);
}

__global__ __launch_bounds__(256) void scatter_kernel(const float* __restrict__ ev,
        const float* __restrict__ denom, const bf16* __restrict__ xjt,
        const int* __restrict__ dst, float* __restrict__ aggr) {
    int e = blockIdx.x, t = threadIdx.x;
    int de = dst[e];
    int h = t >> 6;
    float a = ev[(size_t)e * 4 + h] / (denom[(size_t)de * 4 + h] + 1e-16f);
    float val = a * bf2f(xjt[(size_t)e * DD + t]);
    atomicAdd(aggr + (size_t)de * DD + t, val);
}

__global__ void finalize_kernel(float* __restrict__ h, const float* __restrict__ aggr, int n) {
    for (int i = blockIdx.x * blockDim.x + threadIdx.x; i < n; i += gridDim.x * blockDim.x)
        h[i] = h[i] + gelu_f(aggr[i]);
}

extern "C" void kernel_launch(void* const* d_in, const int* in_sizes, int n_in,
                              void* d_out, int out_size, void* d_ws, size_t ws_size,
                              hipStream_t stream) {
    const float* x    = (const float*)d_in[0];
    const int*   ei   = (const int*)d_in[1];
    const int*   ekg  = (const int*)d_in[2];
    const float* beta = (const float*)d_in[3];
    const float* rel  = (const float*)d_in[4];
    const float* ln_g = (const float*)d_in[5];
    const float* ln_b = (const float*)d_in[6];
    const float* Wt   = (const float*)d_in[7];
    const float* bt   = (const float*)d_in[8];
    const float* Wq   = (const float*)d_in[9];
    const float* bq   = (const float*)d_in[10];
    const float* Wk   = (const float*)d_in[11];
    const float* bk   = (const float*)d_in[12];

    float* h = (float*)d_out;   // residual stream (f32) in d_out

    const int* srcp = ei;
    const int* dstp = ei + NE;
    const int* kgs  = ekg;
    const int* kgd  = ekg + NE;

    char* w = (char*)d_ws;
    float*  aggr  = (float*)w;  w += (size_t)NN * DD * 4;      // 51.2 MB
    float*  att   = (float*)w;  w += (size_t)NE * 4 * 4;       //  4.8 MB
    float*  m_buf = (float*)w;  w += (size_t)NN * 4 * 4;
    float*  denom = (float*)w;  w += (size_t)NN * 4 * 4;
    bf16*   hn    = (bf16*)w;   w += (size_t)NN * DD * 2;      // 25.6 MB
    bf16*   xjt   = (bf16*)w;   w += (size_t)NE * DD * 2;      // 153.6 MB
    ushort* relb  = (ushort*)w; w += (size_t)NE * DD * 2;      // 153.6 MB
    ushort* WtT   = (ushort*)w; w += (size_t)4 * 256 * 512 * 2; // 1 MB
    ushort* WqT   = (ushort*)w; w += (size_t)4 * 256 * 256 * 2;
    ushort* WkT   = (ushort*)w; w += (size_t)4 * 256 * 256 * 2;

    // one-time prep (re-run every launch; deterministic)
    cast_x_kernel<<<2048, 256, 0, stream>>>(x, h, NN * DD / 4);
    f2b_vec_kernel<<<2048, 256, 0, stream>>>(rel, relb, (long)NE * DD / 4);
    transpose_w_kernel<<<512, 256, 0, stream>>>(Wt, WtT, 9, (long)4 * 256 * 512);
    transpose_w_kernel<<<256, 256, 0, stream>>>(Wq, WqT, 8, (long)4 * 256 * 256);
    transpose_w_kernel<<<256, 256, 0, stream>>>(Wk, WkT, 8, (long)4 * 256 * 256);

    const int EB = (NE + 63) / 64;   // 4688
    for (int l = 0; l < 2; ++l) {
        ln_kernel<<<NN, 64, 0, stream>>>(h, ln_g + l * DD, ln_b + l * DD, hn);
        transfer_mfma<<<EB, 512, 0, stream>>>(hn, relb, srcp, kgs,
                WtT + (size_t)l * 2 * 256 * 512, bt + l * 512, xjt);
        qkatt_mfma<<<EB, 512, 0, stream>>>(hn, xjt, dstp, kgd, kgs,
                WqT + (size_t)l * 2 * 256 * 256, bq + l * 512,
                WkT + (size_t)l * 2 * 256 * 256, bk + l * 512, beta, att);
        fill_kernel<<<256, 256, 0, stream>>>(m_buf, -1e30f, NN * 4);
        fill_kernel<<<256, 256, 0, stream>>>(denom, 0.f, NN * 4);
        fill_kernel<<<2048, 256, 0, stream>>>(aggr, 0.f, NN * DD);
        segmax_kernel<<<(NE * 4 + 255) / 256, 256, 0, stream>>>(att, dstp, m_buf);
        expsum_kernel<<<(NE * 4 + 255) / 256, 256, 0, stream>>>(att, dstp, m_buf, denom);
        scatter_kernel<<<NE, 256, 0, stream>>>(att, denom, xjt, dstp, aggr);
        finalize_kernel<<<2048, 256, 0, stream>>>(h, aggr, NN * DD);
    }
}

// Round 4
// 2257.014 us; speedup vs baseline: 4.3671x; 1.0155x over previous
//
#include <hip/hip_runtime.h>
#include <hip/hip_bf16.h>

#define NN 50000
#define NE 300000
#define DD 256

typedef __hip_bfloat16 bf16;
typedef __attribute__((ext_vector_type(8))) short bf16x8;
typedef __attribute__((ext_vector_type(4))) float f32x4;

__device__ __forceinline__ float bf2f(bf16 v) { return __bfloat162float(v); }
__device__ __forceinline__ unsigned short f2b(float v) {
    bf16 t = __float2bfloat16(v);
    return *reinterpret_cast<unsigned short*>(&t);
}
__device__ __forceinline__ float b2f_bits(unsigned short u) {
    return __uint_as_float(((unsigned)u) << 16);
}
__device__ __forceinline__ float gelu_f(float v) {
    return 0.5f * v * (1.f + erff(v * 0.70710678118654752f));
}
__device__ __forceinline__ void atomicMaxF(float* addr, float v) {
    if (v >= 0.f) atomicMax((int*)addr, __float_as_int(v));
    else          atomicMin((unsigned int*)addr, __float_as_uint(v));
}

// ---------------- prep kernels ----------------
__global__ void cast_x_kernel(const float* __restrict__ x, float* __restrict__ h, int n4) {
    for (int i = blockIdx.x * blockDim.x + threadIdx.x; i < n4; i += gridDim.x * blockDim.x)
        ((float4*)h)[i] = ((const float4*)x)[i];
}

__global__ void f2b_vec_kernel(const float* __restrict__ in, ushort* __restrict__ out, long n4) {
    long i0 = (long)blockIdx.x * blockDim.x + threadIdx.x;
    long stride = (long)gridDim.x * blockDim.x;
    for (long i = i0; i < n4; i += stride) {
        float4 v = ((const float4*)in)[i];
        ushort4 o;
        o.x = f2b(v.x); o.y = f2b(v.y); o.z = f2b(v.z); o.w = f2b(v.w);
        ((ushort4*)out)[i] = o;
    }
}

// out[s][o][d] = bf16(in[s][d][o]), dout = 256, din = 1<<shift
__global__ void transpose_w_kernel(const float* __restrict__ in, ushort* __restrict__ out,
                                   int shift, long total) {
    long i0 = (long)blockIdx.x * blockDim.x + threadIdx.x;
    long stride = (long)gridDim.x * blockDim.x;
    long dmask = ((long)1 << shift) - 1;
    for (long i = i0; i < total; i += stride) {
        long d = i & dmask;
        long rest = i >> shift;
        long o = rest & 255;
        long s = rest >> 8;
        out[i] = f2b(in[((s << shift) + d) * 256 + o]);
    }
}

__global__ void fill_kernel(float* __restrict__ p, float v, int n) {
    for (int i = blockIdx.x * blockDim.x + threadIdx.x; i < n; i += gridDim.x * blockDim.x)
        p[i] = v;
}

// ---------------- layernorm ----------------
__global__ __launch_bounds__(64) void ln_kernel(const float* __restrict__ h,
        const float* __restrict__ g, const float* __restrict__ b, bf16* __restrict__ hn) {
    int n = blockIdx.x, t = threadIdx.x;
    float4 v = ((const float4*)(h + (size_t)n * DD))[t];
    float s  = v.x + v.y + v.z + v.w;
    float s2 = v.x * v.x + v.y * v.y + v.z * v.z + v.w * v.w;
    #pragma unroll
    for (int off = 32; off; off >>= 1) {
        s  += __shfl_down(s, off);
        s2 += __shfl_down(s2, off);
    }
    s = __shfl(s, 0); s2 = __shfl(s2, 0);
    float mu  = s * (1.f / DD);
    float var = s2 * (1.f / DD) - mu * mu;
    float rs  = rsqrtf(var + 1e-5f);
    float vv[4] = {v.x, v.y, v.z, v.w};
    ushort4 pk;
    unsigned short* pku = (unsigned short*)&pk;
    #pragma unroll
    for (int j = 0; j < 4; ++j) {
        int c = t * 4 + j;
        pku[j] = f2b((vv[j] - mu) * rs * g[c] + b[c]);
    }
    ((ushort4*)(hn + (size_t)n * DD))[t] = pk;
}

// ---------------- transfer: xjt = gelu(concat(hn[src],rel) @ Wt[kg] + bt[kg]) ----------------
// MFMA: A = WtT[br][o][k] (M=outputs), B = X[e][k] (N=edges), D[o][e]
// LDS X rows 1024B, 16B slot c stored at c ^ (r&7)  (T2 xor-swizzle)
__global__ __launch_bounds__(512) void transfer_mfma(
        const bf16* __restrict__ hn, const ushort* __restrict__ relb,
        const int* __restrict__ src, const int* __restrict__ kg,
        const ushort* __restrict__ WtT, const float* __restrict__ bt,
        bf16* __restrict__ xjt) {
    __shared__ uint4 xs[64 * 64];       // 64 rows x 1024B, swizzled
    __shared__ float bts[2][256];
    __shared__ int skg[64];
    int t = threadIdx.x;
    int e0 = blockIdx.x * 64;
    int wave = t >> 6, lane = t & 63;
    if (t < 256) { bts[0][t] = bt[t]; bts[1][t] = bt[256 + t]; }
    else if (t < 320) {
        int r = t - 256;
        int ge = e0 + r; if (ge >= NE) ge = NE - 1;
        skg[r] = kg[ge];
    }
    const uint4* hn4 = (const uint4*)hn;    // 32 chunks / row
    const uint4* rl4 = (const uint4*)relb;
    #pragma unroll
    for (int i = 0; i < 8; ++i) {
        int r = i * 8 + wave;
        int ge = e0 + r; if (ge >= NE) ge = NE - 1;
        uint4 v;
        if (lane < 32) v = hn4[(size_t)src[ge] * 32 + lane];
        else           v = rl4[(size_t)ge * 32 + (lane - 32)];
        xs[r * 64 + (lane ^ (r & 7))] = v;
    }
    __syncthreads();
    int lr = lane & 15, lg = lane >> 4;
    f32x4 acc[2][2][4];
    #pragma unroll
    for (int b = 0; b < 2; ++b)
        #pragma unroll
        for (int m = 0; m < 2; ++m)
            #pragma unroll
            for (int n = 0; n < 4; ++n) acc[b][m][n] = (f32x4){0.f, 0.f, 0.f, 0.f};
    const char* xsb = (const char*)xs;
    const ushort* wrow0 = WtT + (size_t)(wave * 32 + lr) * 512 + lg * 8;        // m=0
    const ushort* wrow1 = WtT + (size_t)(wave * 32 + 16 + lr) * 512 + lg * 8;   // m=1
    // A double-buffer: X = current, Y = next
    bf16x8 aX[2][2], aY[2][2];   // [br][m]
    aX[0][0] = *(const bf16x8*)(wrow0);            aX[1][0] = *(const bf16x8*)(wrow0 + 131072);
    aX[0][1] = *(const bf16x8*)(wrow1);            aX[1][1] = *(const bf16x8*)(wrow1 + 131072);
    #pragma unroll 1
    for (int kk = 0; kk < 16; kk += 2) {
        // prefetch kk+1 into Y
        {
            int kn = kk + 1;
            const ushort* p0 = wrow0 + kn * 32;
            const ushort* p1 = wrow1 + kn * 32;
            aY[0][0] = *(const bf16x8*)(p0);       aY[1][0] = *(const bf16x8*)(p0 + 131072);
            aY[0][1] = *(const bf16x8*)(p1);       aY[1][1] = *(const bf16x8*)(p1 + 131072);
        }
        {
            bf16x8 bfr[4];
            #pragma unroll
            for (int n = 0; n < 4; ++n) {
                int r = n * 16 + lr;
                bfr[n] = *(const bf16x8*)(xsb + r * 1024 + ((((kk) * 4 + lg) ^ (r & 7)) << 4));
            }
            #pragma unroll
            for (int m = 0; m < 2; ++m)
                #pragma unroll
                for (int n = 0; n < 4; ++n) {
                    acc[0][m][n] = __builtin_amdgcn_mfma_f32_16x16x32_bf16(aX[0][m], bfr[n], acc[0][m][n], 0, 0, 0);
                    acc[1][m][n] = __builtin_amdgcn_mfma_f32_16x16x32_bf16(aX[1][m], bfr[n], acc[1][m][n], 0, 0, 0);
                }
        }
        // prefetch kk+2 into X
        {
            int kn = (kk + 2 < 16) ? kk + 2 : 15;
            const ushort* p0 = wrow0 + kn * 32;
            const ushort* p1 = wrow1 + kn * 32;
            aX[0][0] = *(const bf16x8*)(p0);       aX[1][0] = *(const bf16x8*)(p0 + 131072);
            aX[0][1] = *(const bf16x8*)(p1);       aX[1][1] = *(const bf16x8*)(p1 + 131072);
        }
        {
            bf16x8 bfr[4];
            #pragma unroll
            for (int n = 0; n < 4; ++n) {
                int r = n * 16 + lr;
                bfr[n] = *(const bf16x8*)(xsb + r * 1024 + ((((kk + 1) * 4 + lg) ^ (r & 7)) << 4));
            }
            #pragma unroll
            for (int m = 0; m < 2; ++m)
                #pragma unroll
                for (int n = 0; n < 4; ++n) {
                    acc[0][m][n] = __builtin_amdgcn_mfma_f32_16x16x32_bf16(aY[0][m], bfr[n], acc[0][m][n], 0, 0, 0);
                    acc[1][m][n] = __builtin_amdgcn_mfma_f32_16x16x32_bf16(aY[1][m], bfr[n], acc[1][m][n], 0, 0, 0);
                }
        }
    }
    __syncthreads();
    // epilogue: select branch, add bias, gelu, pack bf16 into swizzled 512B rows
    char* xob = (char*)xs;
    #pragma unroll
    for (int n = 0; n < 4; ++n) {
        int e = n * 16 + lr;
        int kge = skg[e];
        #pragma unroll
        for (int m = 0; m < 2; ++m) {
            int ob = wave * 32 + m * 16 + lg * 4;
            f32x4 a = kge ? acc[1][m][n] : acc[0][m][n];
            ushort4 pk;
            unsigned short* pu = (unsigned short*)&pk;
            #pragma unroll
            for (int r = 0; r < 4; ++r) {
                float bb = kge ? bts[1][ob + r] : bts[0][ob + r];
                pu[r] = f2b(gelu_f(a[r] + bb));
            }
            int bofs = ob * 2;                       // byte col in 512B row
            int slot = ((bofs >> 4) ^ (e & 7));
            *(ushort4*)(xob + e * 512 + slot * 16 + (bofs & 15)) = pk;
        }
    }
    __syncthreads();
    uint4* xjv = (uint4*)xjt;
    #pragma unroll
    for (int i = 0; i < 4; ++i) {
        int flat = i * 512 + t;
        int r = flat >> 5, c = flat & 31;
        int ge = e0 + r;
        if (ge < NE)
            xjv[(size_t)ge * 32 + c] = *(const uint4*)(xob + r * 512 + ((c ^ (r & 7)) << 4));
    }
}

// ---------------- qkatt: att[e][h] = (Wq[kgd]hn[dst] + bq) . (Wk[kgs]xjt + bk) * beta/8 ----------------
// k kept in registers (same lane mapping as q) -> lane-local dot, no LDS round-trip
__global__ __launch_bounds__(512) void qkatt_mfma(
        const bf16* __restrict__ hn, const bf16* __restrict__ xjt,
        const int* __restrict__ dst, const int* __restrict__ kgd, const int* __restrict__ kgs,
        const ushort* __restrict__ WqT, const float* __restrict__ bq,
        const ushort* __restrict__ WkT, const float* __restrict__ bk,
        const float* __restrict__ beta, float* __restrict__ att) {
    __shared__ uint4 xi4[64 * 32];   // hn[dst], 512B rows, swizzled
    __shared__ uint4 xj4[64 * 32];   // xjt rows, swizzled
    __shared__ float bqs[2][256], bks[2][256];
    __shared__ float patt[8][64];
    __shared__ int sgd[64], sgs[64];
    int t = threadIdx.x;
    int e0 = blockIdx.x * 64;
    int wave = t >> 6, lane = t & 63;
    if (t < 256) {
        bqs[0][t] = bq[t]; bqs[1][t] = bq[256 + t];
        bks[0][t] = bk[t]; bks[1][t] = bk[256 + t];
    } else if (t < 320) {
        int r = t - 256;
        int ge = e0 + r; if (ge >= NE) ge = NE - 1;
        sgd[r] = kgd[ge]; sgs[r] = kgs[ge];
    }
    const uint4* hnv = (const uint4*)hn;
    const uint4* xjv = (const uint4*)xjt;
    #pragma unroll
    for (int i = 0; i < 4; ++i) {
        int r = i * 16 + wave * 2 + (lane >> 5);
        int c = lane & 31;
        int ge = e0 + r; if (ge >= NE) ge = NE - 1;
        int sl = (c ^ (r & 7));
        xi4[r * 32 + sl] = hnv[(size_t)dst[ge] * 32 + c];
        xj4[r * 32 + sl] = xjv[(size_t)ge * 32 + c];
    }
    __syncthreads();
    int lr = lane & 15, lg = lane >> 4;
    const ushort* krow0 = WkT + (size_t)(wave * 32 + lr) * 256 + lg * 8;
    const ushort* krow1 = WkT + (size_t)(wave * 32 + 16 + lr) * 256 + lg * 8;
    const ushort* qrow0 = WqT + (size_t)(wave * 32 + lr) * 256 + lg * 8;
    const ushort* qrow1 = WqT + (size_t)(wave * 32 + 16 + lr) * 256 + lg * 8;
    // ---- k-pass ----
    f32x4 kacc[2][2][4];
    #pragma unroll
    for (int b = 0; b < 2; ++b)
        #pragma unroll
        for (int m = 0; m < 2; ++m)
            #pragma unroll
            for (int n = 0; n < 4; ++n) kacc[b][m][n] = (f32x4){0.f, 0.f, 0.f, 0.f};
    const char* xjb = (const char*)xj4;
    {
        bf16x8 aX[2][2], aY[2][2];
        aX[0][0] = *(const bf16x8*)(krow0);        aX[1][0] = *(const bf16x8*)(krow0 + 65536);
        aX[0][1] = *(const bf16x8*)(krow1);        aX[1][1] = *(const bf16x8*)(krow1 + 65536);
        #pragma unroll 1
        for (int kk = 0; kk < 8; kk += 2) {
            {
                const ushort* p0 = krow0 + (kk + 1) * 32;
                const ushort* p1 = krow1 + (kk + 1) * 32;
                aY[0][0] = *(const bf16x8*)(p0);   aY[1][0] = *(const bf16x8*)(p0 + 65536);
                aY[0][1] = *(const bf16x8*)(p1);   aY[1][1] = *(const bf16x8*)(p1 + 65536);
            }
            {
                bf16x8 bfr[4];
                #pragma unroll
                for (int n = 0; n < 4; ++n) {
                    int r = n * 16 + lr;
                    bfr[n] = *(const bf16x8*)(xjb + r * 512 + (((kk * 4 + lg) ^ (r & 7)) << 4));
                }
                #pragma unroll
                for (int m = 0; m < 2; ++m)
                    #pragma unroll
                    for (int n = 0; n < 4; ++n) {
                        kacc[0][m][n] = __builtin_amdgcn_mfma_f32_16x16x32_bf16(aX[0][m], bfr[n], kacc[0][m][n], 0, 0, 0);
                        kacc[1][m][n] = __builtin_amdgcn_mfma_f32_16x16x32_bf16(aX[1][m], bfr[n], kacc[1][m][n], 0, 0, 0);
                    }
            }
            {
                int kn = (kk + 2 < 8) ? kk + 2 : 7;
                const ushort* p0 = krow0 + kn * 32;
                const ushort* p1 = krow1 + kn * 32;
                aX[0][0] = *(const bf16x8*)(p0);   aX[1][0] = *(const bf16x8*)(p0 + 65536);
                aX[0][1] = *(const bf16x8*)(p1);   aX[1][1] = *(const bf16x8*)(p1 + 65536);
            }
            {
                bf16x8 bfr[4];
                #pragma unroll
                for (int n = 0; n < 4; ++n) {
                    int r = n * 16 + lr;
                    bfr[n] = *(const bf16x8*)(xjb + r * 512 + ((((kk + 1) * 4 + lg) ^ (r & 7)) << 4));
                }
                #pragma unroll
                for (int m = 0; m < 2; ++m)
                    #pragma unroll
                    for (int n = 0; n < 4; ++n) {
                        kacc[0][m][n] = __builtin_amdgcn_mfma_f32_16x16x32_bf16(aY[0][m], bfr[n], kacc[0][m][n], 0, 0, 0);
                        kacc[1][m][n] = __builtin_amdgcn_mfma_f32_16x16x32_bf16(aY[1][m], bfr[n], kacc[1][m][n], 0, 0, 0);
                    }
            }
        }
    }
    // select k branch + bias, pack to bf16 pairs: kvp[m][n][0..1] (r pairs)
    unsigned kvp[2][4][2];
    #pragma unroll
    for (int n = 0; n < 4; ++n) {
        int e = n * 16 + lr;
        int kge = sgs[e];
        #pragma unroll
        for (int m = 0; m < 2; ++m) {
            int ob = wave * 32 + m * 16 + lg * 4;
            f32x4 a = kge ? kacc[1][m][n] : kacc[0][m][n];
            float v0 = a[0] + (kge ? bks[1][ob + 0] : bks[0][ob + 0]);
            float v1 = a[1] + (kge ? bks[1][ob + 1] : bks[0][ob + 1]);
            float v2 = a[2] + (kge ? bks[1][ob + 2] : bks[0][ob + 2]);
            float v3 = a[3] + (kge ? bks[1][ob + 3] : bks[0][ob + 3]);
            kvp[m][n][0] = (unsigned)f2b(v0) | ((unsigned)f2b(v1) << 16);
            kvp[m][n][1] = (unsigned)f2b(v2) | ((unsigned)f2b(v3) << 16);
        }
    }
    // ---- q-pass ----
    f32x4 qacc[2][2][4];
    #pragma unroll
    for (int b = 0; b < 2; ++b)
        #pragma unroll
        for (int m = 0; m < 2; ++m)
            #pragma unroll
            for (int n = 0; n < 4; ++n) qacc[b][m][n] = (f32x4){0.f, 0.f, 0.f, 0.f};
    const char* xib = (const char*)xi4;
    {
        bf16x8 aX[2][2], aY[2][2];
        aX[0][0] = *(const bf16x8*)(qrow0);        aX[1][0] = *(const bf16x8*)(qrow0 + 65536);
        aX[0][1] = *(const bf16x8*)(qrow1);        aX[1][1] = *(const bf16x8*)(qrow1 + 65536);
        #pragma unroll 1
        for (int kk = 0; kk < 8; kk += 2) {
            {
                const ushort* p0 = qrow0 + (kk + 1) * 32;
                const ushort* p1 = qrow1 + (kk + 1) * 32;
                aY[0][0] = *(const bf16x8*)(p0);   aY[1][0] = *(const bf16x8*)(p0 + 65536);
                aY[0][1] = *(const bf16x8*)(p1);   aY[1][1] = *(const bf16x8*)(p1 + 65536);
            }
            {
                bf16x8 bfr[4];
                #pragma unroll
                for (int n = 0; n < 4; ++n) {
                    int r = n * 16 + lr;
                    bfr[n] = *(const bf16x8*)(xib + r * 512 + (((kk * 4 + lg) ^ (r & 7)) << 4));
                }
                #pragma unroll
                for (int m = 0; m < 2; ++m)
                    #pragma unroll
                    for (int n = 0; n < 4; ++n) {
                        qacc[0][m][n] = __builtin_amdgcn_mfma_f32_16x16x32_bf16(aX[0][m], bfr[n], qacc[0][m][n], 0, 0, 0);
                        qacc[1][m][n] = __builtin_amdgcn_mfma_f32_16x16x32_bf16(aX[1][m], bfr[n], qacc[1][m][n], 0, 0, 0);
                    }
            }
            {
                int kn = (kk + 2 < 8) ? kk + 2 : 7;
                const ushort* p0 = qrow0 + kn * 32;
                const ushort* p1 = qrow1 + kn * 32;
                aX[0][0] = *(const bf16x8*)(p0);   aX[1][0] = *(const bf16x8*)(p0 + 65536);
                aX[0][1] = *(const bf16x8*)(p1);   aX[1][1] = *(const bf16x8*)(p1 + 65536);
            }
            {
                bf16x8 bfr[4];
                #pragma unroll
                for (int n = 0; n < 4; ++n) {
                    int r = n * 16 + lr;
                    bfr[n] = *(const bf16x8*)(xib + r * 512 + ((((kk + 1) * 4 + lg) ^ (r & 7)) << 4));
                }
                #pragma unroll
                for (int m = 0; m < 2; ++m)
                    #pragma unroll
                    for (int n = 0; n < 4; ++n) {
                        qacc[0][m][n] = __builtin_amdgcn_mfma_f32_16x16x32_bf16(aY[0][m], bfr[n], qacc[0][m][n], 0, 0, 0);
                        qacc[1][m][n] = __builtin_amdgcn_mfma_f32_16x16x32_bf16(aY[1][m], bfr[n], qacc[1][m][n], 0, 0, 0);
                    }
            }
        }
    }
    // ---- lane-local q.k partial, then reduce over lg (shfl 16,32) ----
    float p[4];
    #pragma unroll
    for (int n = 0; n < 4; ++n) {
        int e = n * 16 + lr;
        int kgq = sgd[e];
        float s = 0.f;
        #pragma unroll
        for (int m = 0; m < 2; ++m) {
            int ob = wave * 32 + m * 16 + lg * 4;
            f32x4 a = kgq ? qacc[1][m][n] : qacc[0][m][n];
            unsigned k0 = kvp[m][n][0], k1 = kvp[m][n][1];
            s = fmaf(a[0] + (kgq ? bqs[1][ob + 0] : bqs[0][ob + 0]), b2f_bits((unsigned short)(k0 & 0xffff)), s);
            s = fmaf(a[1] + (kgq ? bqs[1][ob + 1] : bqs[0][ob + 1]), b2f_bits((unsigned short)(k0 >> 16)), s);
            s = fmaf(a[2] + (kgq ? bqs[1][ob + 2] : bqs[0][ob + 2]), b2f_bits((unsigned short)(k1 & 0xffff)), s);
            s = fmaf(a[3] + (kgq ? bqs[1][ob + 3] : bqs[0][ob + 3]), b2f_bits((unsigned short)(k1 >> 16)), s);
        }
        p[n] = s;
    }
    #pragma unroll
    for (int n = 0; n < 4; ++n) {
        p[n] += __shfl_xor(p[n], 16);
        p[n] += __shfl_xor(p[n], 32);
    }
    if (lane < 16) {
        #pragma unroll
        for (int n = 0; n < 4; ++n) patt[wave][n * 16 + lr] = p[n];
    }
    __syncthreads();
    if (t < 256) {
        int e = t & 63, h = t >> 6;
        int ge = e0 + e;
        if (ge < NE)
            att[(size_t)ge * 4 + h] = (patt[2 * h][e] + patt[2 * h + 1][e]) * beta[ge] * 0.125f;
    }
}

// ---------------- softmax / aggregate ----------------
__global__ void segmax_kernel(const float* __restrict__ att, const int* __restrict__ dst,
                              float* __restrict__ m) {
    int i = blockIdx.x * blockDim.x + threadIdx.x;
    if (i >= NE * 4) return;
    int e = i >> 2, h = i & 3;
    atomicMaxF(m + (size_t)dst[e] * 4 + h, att[i]);
}

__global__ void expsum_kernel(float* __restrict__ att, const int* __restrict__ dst,
                              const float* __restrict__ m, float* __restrict__ denom) {
    int i = blockIdx.x * blockDim.x + threadIdx.x;
    if (i >= NE * 4) return;
    int e = i >> 2, h = i & 3;
    float v = expf(att[i] - m[(size_t)dst[e] * 4 + h]);
    att[i] = v;
    atomicAdd(denom + (size_t)dst[e] * 4 + h, v);
}

// aggr accumulates UNNORMALIZED sums; division happens in finalize
__global__ __launch_bounds__(256) void scatter_kernel(const float* __restrict__ ev,
        const bf16* __restrict__ xjt, const int* __restrict__ dst, float* __restrict__ aggr) {
    int e = blockIdx.x, t = threadIdx.x;
    int de = dst[e];
    int h = t >> 6;
    float a = ev[(size_t)e * 4 + h];
    atomicAdd(aggr + (size_t)de * DD + t, a * bf2f(xjt[(size_t)e * DD + t]));
}

__global__ void finalize_kernel(float* __restrict__ h, const float* __restrict__ aggr,
                                const float* __restrict__ denom, int n) {
    for (int i = blockIdx.x * blockDim.x + threadIdx.x; i < n; i += gridDim.x * blockDim.x) {
        int node = i >> 8, hh = (i >> 6) & 3;
        float d = denom[(size_t)node * 4 + hh] + 1e-16f;
        h[i] = h[i] + gelu_f(aggr[i] / d);
    }
}

extern "C" void kernel_launch(void* const* d_in, const int* in_sizes, int n_in,
                              void* d_out, int out_size, void* d_ws, size_t ws_size,
                              hipStream_t stream) {
    const float* x    = (const float*)d_in[0];
    const int*   ei   = (const int*)d_in[1];
    const int*   ekg  = (const int*)d_in[2];
    const float* beta = (const float*)d_in[3];
    const float* rel  = (const float*)d_in[4];
    const float* ln_g = (const float*)d_in[5];
    const float* ln_b = (const float*)d_in[6];
    const float* Wt   = (const float*)d_in[7];
    const float* bt   = (const float*)d_in[8];
    const float* Wq   = (const float*)d_in[9];
    const float* bq   = (const float*)d_in[10];
    const float* Wk   = (const float*)d_in[11];
    const float* bk   = (const float*)d_in[12];

    float* h = (float*)d_out;   // residual stream (f32) in d_out

    const int* srcp = ei;
    const int* dstp = ei + NE;
    const int* kgs  = ekg;
    const int* kgd  = ekg + NE;

    char* w = (char*)d_ws;
    float*  aggr  = (float*)w;  w += (size_t)NN * DD * 4;      // 51.2 MB
    float*  att   = (float*)w;  w += (size_t)NE * 4 * 4;       //  4.8 MB
    float*  m_buf = (float*)w;  w += (size_t)NN * 4 * 4;
    float*  denom = (float*)w;  w += (size_t)NN * 4 * 4;
    bf16*   hn    = (bf16*)w;   w += (size_t)NN * DD * 2;      // 25.6 MB
    bf16*   xjt   = (bf16*)w;   w += (size_t)NE * DD * 2;      // 153.6 MB
    ushort* relb  = (ushort*)w; w += (size_t)NE * DD * 2;      // 153.6 MB
    ushort* WtT   = (ushort*)w; w += (size_t)4 * 256 * 512 * 2; // 1 MB
    ushort* WqT   = (ushort*)w; w += (size_t)4 * 256 * 256 * 2;
    ushort* WkT   = (ushort*)w; w += (size_t)4 * 256 * 256 * 2;

    cast_x_kernel<<<2048, 256, 0, stream>>>(x, h, NN * DD / 4);
    f2b_vec_kernel<<<2048, 256, 0, stream>>>(rel, relb, (long)NE * DD / 4);
    transpose_w_kernel<<<512, 256, 0, stream>>>(Wt, WtT, 9, (long)4 * 256 * 512);
    transpose_w_kernel<<<256, 256, 0, stream>>>(Wq, WqT, 8, (long)4 * 256 * 256);
    transpose_w_kernel<<<256, 256, 0, stream>>>(Wk, WkT, 8, (long)4 * 256 * 256);

    const int EB = (NE + 63) / 64;   // 4688
    for (int l = 0; l < 2; ++l) {
        ln_kernel<<<NN, 64, 0, stream>>>(h, ln_g + l * DD, ln_b + l * DD, hn);
        transfer_mfma<<<EB, 512, 0, stream>>>(hn, relb, srcp, kgs,
                WtT + (size_t)l * 2 * 256 * 512, bt + l * 512, xjt);
        qkatt_mfma<<<EB, 512, 0, stream>>>(hn, xjt, dstp, kgd, kgs,
                WqT + (size_t)l * 2 * 256 * 256, bq + l * 512,
                WkT + (size_t)l * 2 * 256 * 256, bk + l * 512, beta, att);
        fill_kernel<<<256, 256, 0, stream>>>(m_buf, -1e30f, NN * 4);
        fill_kernel<<<256, 256, 0, stream>>>(denom, 0.f, NN * 4);
        fill_kernel<<<2048, 256, 0, stream>>>(aggr, 0.f, NN * DD);
        segmax_kernel<<<(NE * 4 + 255) / 256, 256, 0, stream>>>(att, dstp, m_buf);
        expsum_kernel<<<(NE * 4 + 255) / 256, 256, 0, stream>>>(att, dstp, m_buf, denom);
        scatter_kernel<<<NE, 256, 0, stream>>>(att, xjt, dstp, aggr);
        finalize_kernel<<<2048, 256, 0, stream>>>(h, aggr, denom, NN * DD);
    }
}

// Round 5
// 1837.453 us; speedup vs baseline: 5.3643x; 1.2283x over previous
//
#include <hip/hip_runtime.h>
#include <hip/hip_bf16.h>

#define NN 50000
#define NE 300000
#define DD 256
#define NCHUNK 293   // ceil(NE/1024)

typedef __hip_bfloat16 bf16;
typedef __attribute__((ext_vector_type(8))) short bf16x8;
typedef __attribute__((ext_vector_type(4))) float f32x4;

__device__ __forceinline__ float bf2f(bf16 v) { return __bfloat162float(v); }
__device__ __forceinline__ unsigned short f2b(float v) {
    bf16 t = __float2bfloat16(v);
    return *reinterpret_cast<unsigned short*>(&t);
}
__device__ __forceinline__ float b2f_bits(unsigned short u) {
    return __uint_as_float(((unsigned)u) << 16);
}
__device__ __forceinline__ float gelu_f(float v) {
    return 0.5f * v * (1.f + erff(v * 0.70710678118654752f));
}
__device__ __forceinline__ void atomicMaxF(float* addr, float v) {
    if (v >= 0.f) atomicMax((int*)addr, __float_as_int(v));
    else          atomicMin((unsigned int*)addr, __float_as_uint(v));
}

// ---------------- edge partition by kg (stable, deterministic) ----------------
__global__ void part_count(const int* __restrict__ kg, int* __restrict__ bcnt) {
    int base = blockIdx.x * 1024;
    __shared__ int wc[4];
    int t = threadIdx.x, wave = t >> 6, lane = t & 63;
    int cnt = 0;
    #pragma unroll
    for (int s = 0; s < 4; ++s) {
        int j = base + s * 256 + t;
        int is0 = (j < NE && kg[j] == 0) ? 1 : 0;
        unsigned long long m = __ballot(is0);
        if (lane == 0) cnt += __popcll(m);
    }
    if (lane == 0) wc[wave] = cnt;
    __syncthreads();
    if (t == 0) bcnt[blockIdx.x] = wc[0] + wc[1] + wc[2] + wc[3];
}

__global__ void part_scan(const int* __restrict__ bcnt, int* __restrict__ bofs,
                          int* __restrict__ meta, int n) {
    if (threadIdx.x == 0 && blockIdx.x == 0) {
        int run = 0;
        for (int i = 0; i < n; ++i) { bofs[i] = run; run += bcnt[i]; }
        meta[0] = run;
    }
}

__global__ void part_scatter(const int* __restrict__ kg, const int* __restrict__ bofs,
                             const int* __restrict__ meta, int* __restrict__ perm) {
    int base = blockIdx.x * 1024;
    int c0 = meta[0];
    __shared__ int wz[4];
    int t = threadIdx.x, wave = t >> 6, lane = t & 63;
    int zrun = bofs[blockIdx.x];
    for (int s = 0; s < 4; ++s) {
        int j = base + s * 256 + t;
        int valid = j < NE;
        int is0 = (valid && kg[j] == 0) ? 1 : 0;
        unsigned long long m = __ballot(is0);
        int zb = __popcll(m & ((1ull << lane) - 1ull));
        if (lane == 0) wz[wave] = __popcll(m);
        __syncthreads();
        int wbefore = 0;
        for (int w = 0; w < wave; ++w) wbefore += wz[w];
        int zeros_before = zrun + wbefore + zb;
        if (valid) {
            int pos = is0 ? zeros_before : (c0 + (j - zeros_before));
            perm[pos] = j;
        }
        int stepz = wz[0] + wz[1] + wz[2] + wz[3];
        __syncthreads();
        zrun += stepz;
    }
}

// ---------------- prep kernels ----------------
__global__ void cast_x_kernel(const float* __restrict__ x, float* __restrict__ h, int n4) {
    for (int i = blockIdx.x * blockDim.x + threadIdx.x; i < n4; i += gridDim.x * blockDim.x)
        ((float4*)h)[i] = ((const float4*)x)[i];
}

// out[s][o][d] = bf16(in[s][d][o]), dout = 256, din = 1<<shift
__global__ void transpose_w_kernel(const float* __restrict__ in, ushort* __restrict__ out,
                                   int shift, long total) {
    long i0 = (long)blockIdx.x * blockDim.x + threadIdx.x;
    long stride = (long)gridDim.x * blockDim.x;
    long dmask = ((long)1 << shift) - 1;
    for (long i = i0; i < total; i += stride) {
        long d = i & dmask;
        long rest = i >> shift;
        long o = rest & 255;
        long s = rest >> 8;
        out[i] = f2b(in[((s << shift) + d) * 256 + o]);
    }
}

__global__ void fill_kernel(float* __restrict__ p, float v, int n) {
    for (int i = blockIdx.x * blockDim.x + threadIdx.x; i < n; i += gridDim.x * blockDim.x)
        p[i] = v;
}

// ---------------- layernorm ----------------
__global__ __launch_bounds__(64) void ln_kernel(const float* __restrict__ h,
        const float* __restrict__ g, const float* __restrict__ b, bf16* __restrict__ hn) {
    int n = blockIdx.x, t = threadIdx.x;
    float4 v = ((const float4*)(h + (size_t)n * DD))[t];
    float s  = v.x + v.y + v.z + v.w;
    float s2 = v.x * v.x + v.y * v.y + v.z * v.z + v.w * v.w;
    #pragma unroll
    for (int off = 32; off; off >>= 1) {
        s  += __shfl_down(s, off);
        s2 += __shfl_down(s2, off);
    }
    s = __shfl(s, 0); s2 = __shfl(s2, 0);
    float mu  = s * (1.f / DD);
    float var = s2 * (1.f / DD) - mu * mu;
    float rs  = rsqrtf(var + 1e-5f);
    float vv[4] = {v.x, v.y, v.z, v.w};
    ushort4 pk;
    unsigned short* pku = (unsigned short*)&pk;
    #pragma unroll
    for (int j = 0; j < 4; ++j) {
        int c = t * 4 + j;
        pku[j] = f2b((vv[j] - mu) * rs * g[c] + b[c]);
    }
    ((ushort4*)(hn + (size_t)n * DD))[t] = pk;
}

// ---------------- transfer (+fused k): kg-homogeneous tiles via perm ----------------
// xjt = gelu(concat(hn[src],rel) @ Wt[kg] + bt[kg]); k = xjt @ Wk[kg]^T... (WkT[o][k]) + bk
__global__ __launch_bounds__(512) void transfer_mfma(
        const bf16* __restrict__ hn, const float* __restrict__ rel,
        const int* __restrict__ src,
        const int* __restrict__ perm, const int* __restrict__ meta,
        const ushort* __restrict__ WtT, const float* __restrict__ bt,
        const ushort* __restrict__ WkT, const float* __restrict__ bk,
        bf16* __restrict__ xjt, bf16* __restrict__ kout) {
    __shared__ uint4 xs[64 * 64];     // 64 rows x 1024B, xor-swizzled 16B slots
    __shared__ float bts[256], bks[256];
    __shared__ int sge[64], ssrc[64], sval[64];
    int t = threadIdx.x;
    int c0 = meta[0];
    int tiles0 = (c0 + 63) >> 6;
    int tiles1 = (NE - c0 + 63) >> 6;
    int bid = blockIdx.x;
    if (bid >= tiles0 + tiles1) return;
    int kgt, start, end;
    if (bid < tiles0) { kgt = 0; start = bid * 64; end = c0; }
    else              { kgt = 1; start = c0 + (bid - tiles0) * 64; end = NE; }
    int wave = t >> 6, lane = t & 63;
    if (t < 64) {
        int pos = start + t;
        int v = pos < end;
        int cp = v ? pos : end - 1;
        int ge = perm[cp];
        sge[t] = ge; sval[t] = v; ssrc[t] = src[ge];
    } else if (t >= 256) {
        int c = t - 256;
        bts[c] = bt[kgt * 256 + c];
        bks[c] = bk[kgt * 256 + c];
    }
    __syncthreads();
    const uint4* hn4 = (const uint4*)hn;
    #pragma unroll
    for (int i = 0; i < 8; ++i) {
        int r = i * 8 + wave;
        uint4 v;
        if (lane < 32) {
            v = hn4[(size_t)ssrc[r] * 32 + lane];
        } else {
            int c2 = lane - 32;
            const float4* rp = (const float4*)(rel + (size_t)sge[r] * 256) + c2 * 2;
            float4 fa = rp[0], fb = rp[1];
            v.x = (unsigned)f2b(fa.x) | ((unsigned)f2b(fa.y) << 16);
            v.y = (unsigned)f2b(fa.z) | ((unsigned)f2b(fa.w) << 16);
            v.z = (unsigned)f2b(fb.x) | ((unsigned)f2b(fb.y) << 16);
            v.w = (unsigned)f2b(fb.z) | ((unsigned)f2b(fb.w) << 16);
        }
        xs[r * 64 + (lane ^ (r & 7))] = v;
    }
    __syncthreads();
    int lr = lane & 15, lg = lane >> 4;
    f32x4 acc[2][4];
    #pragma unroll
    for (int m = 0; m < 2; ++m)
        #pragma unroll
        for (int n = 0; n < 4; ++n) acc[m][n] = (f32x4){0.f, 0.f, 0.f, 0.f};
    const char* xsb = (const char*)xs;
    const ushort* wb = WtT + (size_t)kgt * 131072;   // 256*512
    const ushort* wrow0 = wb + (size_t)(wave * 32 + lr) * 512 + lg * 8;
    const ushort* wrow1 = wb + (size_t)(wave * 32 + 16 + lr) * 512 + lg * 8;
    bf16x8 aX[2], aY[2];
    aX[0] = *(const bf16x8*)wrow0;
    aX[1] = *(const bf16x8*)wrow1;
    #pragma unroll 1
    for (int kk = 0; kk < 16; kk += 2) {
        aY[0] = *(const bf16x8*)(wrow0 + (kk + 1) * 32);
        aY[1] = *(const bf16x8*)(wrow1 + (kk + 1) * 32);
        {
            bf16x8 bfr[4];
            #pragma unroll
            for (int n = 0; n < 4; ++n) {
                int r = n * 16 + lr;
                bfr[n] = *(const bf16x8*)(xsb + r * 1024 + (((kk * 4 + lg) ^ (r & 7)) << 4));
            }
            #pragma unroll
            for (int m = 0; m < 2; ++m)
                #pragma unroll
                for (int n = 0; n < 4; ++n)
                    acc[m][n] = __builtin_amdgcn_mfma_f32_16x16x32_bf16(aX[m], bfr[n], acc[m][n], 0, 0, 0);
        }
        {
            int kn = (kk + 2 < 16) ? kk + 2 : 15;
            aX[0] = *(const bf16x8*)(wrow0 + kn * 32);
            aX[1] = *(const bf16x8*)(wrow1 + kn * 32);
        }
        {
            bf16x8 bfr[4];
            #pragma unroll
            for (int n = 0; n < 4; ++n) {
                int r = n * 16 + lr;
                bfr[n] = *(const bf16x8*)(xsb + r * 1024 + ((((kk + 1) * 4 + lg) ^ (r & 7)) << 4));
            }
            #pragma unroll
            for (int m = 0; m < 2; ++m)
                #pragma unroll
                for (int n = 0; n < 4; ++n)
                    acc[m][n] = __builtin_amdgcn_mfma_f32_16x16x32_bf16(aY[m], bfr[n], acc[m][n], 0, 0, 0);
        }
    }
    __syncthreads();
    // epilogue: bias + gelu, pack bf16 into swizzled 512B rows (reuse xs)
    char* xob = (char*)xs;
    #pragma unroll
    for (int n = 0; n < 4; ++n) {
        int e = n * 16 + lr;
        #pragma unroll
        for (int m = 0; m < 2; ++m) {
            int ob = wave * 32 + m * 16 + lg * 4;
            f32x4 a = acc[m][n];
            ushort4 pk;
            unsigned short* pu = (unsigned short*)&pk;
            #pragma unroll
            for (int r = 0; r < 4; ++r)
                pu[r] = f2b(gelu_f(a[r] + bts[ob + r]));
            int bofs = ob * 2;
            int slot = ((bofs >> 4) ^ (e & 7));
            *(ushort4*)(xob + e * 512 + slot * 16 + (bofs & 15)) = pk;
        }
    }
    __syncthreads();
    // ---- fused k-pass: k = Wk[kg] @ xjt_tile + bk ----
    f32x4 kc[2][4];
    #pragma unroll
    for (int m = 0; m < 2; ++m)
        #pragma unroll
        for (int n = 0; n < 4; ++n) kc[m][n] = (f32x4){0.f, 0.f, 0.f, 0.f};
    const ushort* kb = WkT + (size_t)kgt * 65536;    // 256*256
    const ushort* kr0 = kb + (size_t)(wave * 32 + lr) * 256 + lg * 8;
    const ushort* kr1 = kb + (size_t)(wave * 32 + 16 + lr) * 256 + lg * 8;
    #pragma unroll
    for (int kk = 0; kk < 8; ++kk) {
        bf16x8 a0 = *(const bf16x8*)(kr0 + kk * 32);
        bf16x8 a1 = *(const bf16x8*)(kr1 + kk * 32);
        bf16x8 bfr[4];
        #pragma unroll
        for (int n = 0; n < 4; ++n) {
            int r = n * 16 + lr;
            bfr[n] = *(const bf16x8*)(xob + r * 512 + (((kk * 4 + lg) ^ (r & 7)) << 4));
        }
        #pragma unroll
        for (int n = 0; n < 4; ++n) {
            kc[0][n] = __builtin_amdgcn_mfma_f32_16x16x32_bf16(a0, bfr[n], kc[0][n], 0, 0, 0);
            kc[1][n] = __builtin_amdgcn_mfma_f32_16x16x32_bf16(a1, bfr[n], kc[1][n], 0, 0, 0);
        }
    }
    // k epilogue: direct 8B global stores
    #pragma unroll
    for (int n = 0; n < 4; ++n) {
        int e = n * 16 + lr;
        if (sval[e]) {
            size_t kro = (size_t)sge[e] * 256;
            #pragma unroll
            for (int m = 0; m < 2; ++m) {
                int ob = wave * 32 + m * 16 + lg * 4;
                f32x4 a = kc[m][n];
                ushort4 pk;
                unsigned short* pu = (unsigned short*)&pk;
                #pragma unroll
                for (int r = 0; r < 4; ++r) pu[r] = f2b(a[r] + bks[ob + r]);
                *(ushort4*)((ushort*)kout + kro + ob) = pk;
            }
        }
    }
    // xjt store from LDS (coalesced 16B)
    uint4* xjv = (uint4*)xjt;
    #pragma unroll
    for (int i = 0; i < 4; ++i) {
        int flat = i * 512 + t;
        int r = flat >> 5, c = flat & 31;
        if (sval[r])
            xjv[(size_t)sge[r] * 32 + c] = *(const uint4*)(xob + r * 512 + ((c ^ (r & 7)) << 4));
    }
}

// ---------------- q-only: att[e][h] = (Wq[kgd]hn[dst] + bq) . k[e] * beta/8 ----------------
__global__ __launch_bounds__(512) void q_mfma(
        const bf16* __restrict__ hn, const bf16* __restrict__ kout,
        const int* __restrict__ dst,
        const int* __restrict__ perm, const int* __restrict__ meta,
        const ushort* __restrict__ WqT, const float* __restrict__ bq,
        const float* __restrict__ beta, float* __restrict__ att) {
    __shared__ uint4 xi4[64 * 32];   // hn[dst], 512B rows, swizzled
    __shared__ float bqs[256];
    __shared__ float patt[8][64];
    __shared__ int sge[64], sdst[64], sval[64];
    int t = threadIdx.x;
    int c0 = meta[0];
    int tiles0 = (c0 + 63) >> 6;
    int tiles1 = (NE - c0 + 63) >> 6;
    int bid = blockIdx.x;
    if (bid >= tiles0 + tiles1) return;
    int kgt, start, end;
    if (bid < tiles0) { kgt = 0; start = bid * 64; end = c0; }
    else              { kgt = 1; start = c0 + (bid - tiles0) * 64; end = NE; }
    int wave = t >> 6, lane = t & 63;
    if (t < 64) {
        int pos = start + t;
        int v = pos < end;
        int cp = v ? pos : end - 1;
        int ge = perm[cp];
        sge[t] = ge; sval[t] = v; sdst[t] = dst[ge];
    } else if (t >= 256) {
        bqs[t - 256] = bq[kgt * 256 + (t - 256)];
    }
    __syncthreads();
    const uint4* hnv = (const uint4*)hn;
    #pragma unroll
    for (int i = 0; i < 4; ++i) {
        int r = i * 16 + wave * 2 + (lane >> 5);
        int c = lane & 31;
        xi4[r * 32 + (c ^ (r & 7))] = hnv[(size_t)sdst[r] * 32 + c];
    }
    __syncthreads();
    int lr = lane & 15, lg = lane >> 4;
    // early k loads (independent of MFMA)
    ushort4 kv[2][4];
    #pragma unroll
    for (int n = 0; n < 4; ++n) {
        int e = n * 16 + lr;
        #pragma unroll
        for (int m = 0; m < 2; ++m) {
            int ob = wave * 32 + m * 16 + lg * 4;
            kv[m][n] = *(const ushort4*)((const ushort*)kout + (size_t)sge[e] * 256 + ob);
        }
    }
    // q MFMA, single branch
    f32x4 qacc[2][4];
    #pragma unroll
    for (int m = 0; m < 2; ++m)
        #pragma unroll
        for (int n = 0; n < 4; ++n) qacc[m][n] = (f32x4){0.f, 0.f, 0.f, 0.f};
    const char* xib = (const char*)xi4;
    const ushort* qb = WqT + (size_t)kgt * 65536;
    const ushort* qr0 = qb + (size_t)(wave * 32 + lr) * 256 + lg * 8;
    const ushort* qr1 = qb + (size_t)(wave * 32 + 16 + lr) * 256 + lg * 8;
    bf16x8 aX[2], aY[2];
    aX[0] = *(const bf16x8*)qr0;
    aX[1] = *(const bf16x8*)qr1;
    #pragma unroll 1
    for (int kk = 0; kk < 8; kk += 2) {
        aY[0] = *(const bf16x8*)(qr0 + (kk + 1) * 32);
        aY[1] = *(const bf16x8*)(qr1 + (kk + 1) * 32);
        {
            bf16x8 bfr[4];
            #pragma unroll
            for (int n = 0; n < 4; ++n) {
                int r = n * 16 + lr;
                bfr[n] = *(const bf16x8*)(xib + r * 512 + (((kk * 4 + lg) ^ (r & 7)) << 4));
            }
            #pragma unroll
            for (int m = 0; m < 2; ++m)
                #pragma unroll
                for (int n = 0; n < 4; ++n)
                    qacc[m][n] = __builtin_amdgcn_mfma_f32_16x16x32_bf16(aX[m], bfr[n], qacc[m][n], 0, 0, 0);
        }
        {
            int kn = (kk + 2 < 8) ? kk + 2 : 7;
            aX[0] = *(const bf16x8*)(qr0 + kn * 32);
            aX[1] = *(const bf16x8*)(qr1 + kn * 32);
        }
        {
            bf16x8 bfr[4];
            #pragma unroll
            for (int n = 0; n < 4; ++n) {
                int r = n * 16 + lr;
                bfr[n] = *(const bf16x8*)(xib + r * 512 + ((((kk + 1) * 4 + lg) ^ (r & 7)) << 4));
            }
            #pragma unroll
            for (int m = 0; m < 2; ++m)
                #pragma unroll
                for (int n = 0; n < 4; ++n)
                    qacc[m][n] = __builtin_amdgcn_mfma_f32_16x16x32_bf16(aY[m], bfr[n], qacc[m][n], 0, 0, 0);
        }
    }
    // lane-local dot q.k then reduce over lg
    float p[4];
    #pragma unroll
    for (int n = 0; n < 4; ++n) {
        float s = 0.f;
        #pragma unroll
        for (int m = 0; m < 2; ++m) {
            int ob = wave * 32 + m * 16 + lg * 4;
            f32x4 a = qacc[m][n];
            ushort4 kk4 = kv[m][n];
            s = fmaf(a[0] + bqs[ob + 0], b2f_bits(kk4.x), s);
            s = fmaf(a[1] + bqs[ob + 1], b2f_bits(kk4.y), s);
            s = fmaf(a[2] + bqs[ob + 2], b2f_bits(kk4.z), s);
            s = fmaf(a[3] + bqs[ob + 3], b2f_bits(kk4.w), s);
        }
        p[n] = s;
    }
    #pragma unroll
    for (int n = 0; n < 4; ++n) {
        p[n] += __shfl_xor(p[n], 16);
        p[n] += __shfl_xor(p[n], 32);
    }
    if (lane < 16) {
        #pragma unroll
        for (int n = 0; n < 4; ++n) patt[wave][n * 16 + lr] = p[n];
    }
    __syncthreads();
    if (t < 256) {
        int e = t & 63, h = t >> 6;
        if (sval[e]) {
            int ge = sge[e];
            att[(size_t)ge * 4 + h] = (patt[2 * h][e] + patt[2 * h + 1][e]) * beta[ge] * 0.125f;
        }
    }
}

// ---------------- softmax / aggregate ----------------
__global__ void segmax_kernel(const float* __restrict__ att, const int* __restrict__ dst,
                              float* __restrict__ m) {
    int i = blockIdx.x * blockDim.x + threadIdx.x;
    if (i >= NE * 4) return;
    int e = i >> 2, h = i & 3;
    atomicMaxF(m + (size_t)dst[e] * 4 + h, att[i]);
}

__global__ void expsum_kernel(float* __restrict__ att, const int* __restrict__ dst,
                              const float* __restrict__ m, float* __restrict__ denom) {
    int i = blockIdx.x * blockDim.x + threadIdx.x;
    if (i >= NE * 4) return;
    int e = i >> 2, h = i & 3;
    float v = expf(att[i] - m[(size_t)dst[e] * 4 + h]);
    att[i] = v;
    atomicAdd(denom + (size_t)dst[e] * 4 + h, v);
}

// aggr accumulates UNNORMALIZED sums; division happens in finalize
__global__ __launch_bounds__(256) void scatter_kernel(const float* __restrict__ ev,
        const bf16* __restrict__ xjt, const int* __restrict__ dst, float* __restrict__ aggr) {
    int e = blockIdx.x, t = threadIdx.x;
    int de = dst[e];
    int h = t >> 6;
    float a = ev[(size_t)e * 4 + h];
    atomicAdd(aggr + (size_t)de * DD + t, a * bf2f(xjt[(size_t)e * DD + t]));
}

__global__ void finalize_kernel(float* __restrict__ h, const float* __restrict__ aggr,
                                const float* __restrict__ denom, int n) {
    for (int i = blockIdx.x * blockDim.x + threadIdx.x; i < n; i += gridDim.x * blockDim.x) {
        int node = i >> 8, hh = (i >> 6) & 3;
        float d = denom[(size_t)node * 4 + hh] + 1e-16f;
        h[i] = h[i] + gelu_f(aggr[i] / d);
    }
}

extern "C" void kernel_launch(void* const* d_in, const int* in_sizes, int n_in,
                              void* d_out, int out_size, void* d_ws, size_t ws_size,
                              hipStream_t stream) {
    const float* x    = (const float*)d_in[0];
    const int*   ei   = (const int*)d_in[1];
    const int*   ekg  = (const int*)d_in[2];
    const float* beta = (const float*)d_in[3];
    const float* rel  = (const float*)d_in[4];
    const float* ln_g = (const float*)d_in[5];
    const float* ln_b = (const float*)d_in[6];
    const float* Wt   = (const float*)d_in[7];
    const float* bt   = (const float*)d_in[8];
    const float* Wq   = (const float*)d_in[9];
    const float* bq   = (const float*)d_in[10];
    const float* Wk   = (const float*)d_in[11];
    const float* bk   = (const float*)d_in[12];

    float* h = (float*)d_out;   // residual stream (f32) in d_out

    const int* srcp = ei;
    const int* dstp = ei + NE;
    const int* kgs  = ekg;
    const int* kgd  = ekg + NE;

    char* w = (char*)d_ws;
    float*  aggr  = (float*)w;  w += (size_t)NN * DD * 4;        // 51.2 MB
    float*  att   = (float*)w;  w += (size_t)NE * 4 * 4;         //  4.8 MB
    float*  m_buf = (float*)w;  w += (size_t)NN * 4 * 4;
    float*  denom = (float*)w;  w += (size_t)NN * 4 * 4;
    bf16*   hn    = (bf16*)w;   w += (size_t)NN * DD * 2;        // 25.6 MB
    bf16*   xjt   = (bf16*)w;   w += (size_t)NE * DD * 2;        // 153.6 MB
    bf16*   kout  = (bf16*)w;   w += (size_t)NE * DD * 2;        // 153.6 MB
    ushort* WtT   = (ushort*)w; w += (size_t)4 * 256 * 512 * 2;  // 1 MB
    ushort* WqT   = (ushort*)w; w += (size_t)4 * 256 * 256 * 2;
    ushort* WkT   = (ushort*)w; w += (size_t)4 * 256 * 256 * 2;
    int* perm_src = (int*)w;    w += (size_t)NE * 4;             // 1.2 MB
    int* perm_dst = (int*)w;    w += (size_t)NE * 4;
    int* bcnt0    = (int*)w;    w += NCHUNK * 4;
    int* bofs0    = (int*)w;    w += NCHUNK * 4;
    int* bcnt1    = (int*)w;    w += NCHUNK * 4;
    int* bofs1    = (int*)w;    w += NCHUNK * 4;
    int* meta0    = (int*)w;    w += 16;
    int* meta1    = (int*)w;    w += 16;

    // edge partitions (static across layers)
    part_count<<<NCHUNK, 256, 0, stream>>>(kgs, bcnt0);
    part_scan<<<1, 64, 0, stream>>>(bcnt0, bofs0, meta0, NCHUNK);
    part_scatter<<<NCHUNK, 256, 0, stream>>>(kgs, bofs0, meta0, perm_src);
    part_count<<<NCHUNK, 256, 0, stream>>>(kgd, bcnt1);
    part_scan<<<1, 64, 0, stream>>>(bcnt1, bofs1, meta1, NCHUNK);
    part_scatter<<<NCHUNK, 256, 0, stream>>>(kgd, bofs1, meta1, perm_dst);

    cast_x_kernel<<<2048, 256, 0, stream>>>(x, h, NN * DD / 4);
    transpose_w_kernel<<<512, 256, 0, stream>>>(Wt, WtT, 9, (long)4 * 256 * 512);
    transpose_w_kernel<<<256, 256, 0, stream>>>(Wq, WqT, 8, (long)4 * 256 * 256);
    transpose_w_kernel<<<256, 256, 0, stream>>>(Wk, WkT, 8, (long)4 * 256 * 256);

    const int EBP = (NE + 126) / 64;   // max tiles over both partitions (4689)
    for (int l = 0; l < 2; ++l) {
        ln_kernel<<<NN, 64, 0, stream>>>(h, ln_g + l * DD, ln_b + l * DD, hn);
        transfer_mfma<<<EBP, 512, 0, stream>>>(hn, rel, srcp, perm_src, meta0,
                WtT + (size_t)l * 2 * 256 * 512, bt + l * 512,
                WkT + (size_t)l * 2 * 256 * 256, bk + l * 512, xjt, kout);
        q_mfma<<<EBP, 512, 0, stream>>>(hn, kout, dstp, perm_dst, meta1,
                WqT + (size_t)l * 2 * 256 * 256, bq + l * 512, beta, att);
        fill_kernel<<<256, 256, 0, stream>>>(m_buf, -1e30f, NN * 4);
        fill_kernel<<<256, 256, 0, stream>>>(denom, 0.f, NN * 4);
        fill_kernel<<<2048, 256, 0, stream>>>(aggr, 0.f, NN * DD);
        segmax_kernel<<<(NE * 4 + 255) / 256, 256, 0, stream>>>(att, dstp, m_buf);
        expsum_kernel<<<(NE * 4 + 255) / 256, 256, 0, stream>>>(att, dstp, m_buf, denom);
        scatter_kernel<<<NE, 256, 0, stream>>>(att, xjt, dstp, aggr);
        finalize_kernel<<<2048, 256, 0, stream>>>(h, aggr, denom, NN * DD);
    }
}

// Round 6
// 1590.815 us; speedup vs baseline: 6.1960x; 1.1550x over previous
//
#include <hip/hip_runtime.h>
#include <hip/hip_bf16.h>

#define NN 50000
#define NE 300000
#define DD 256
#define NCHUNK 293   // ceil(NE/1024)

typedef __hip_bfloat16 bf16;
typedef __attribute__((ext_vector_type(8))) short bf16x8;
typedef __attribute__((ext_vector_type(4))) float f32x4;

__device__ __forceinline__ float bf2f(bf16 v) { return __bfloat162float(v); }
__device__ __forceinline__ unsigned short f2b(float v) {
    bf16 t = __float2bfloat16(v);
    return *reinterpret_cast<unsigned short*>(&t);
}
__device__ __forceinline__ float b2f_bits(unsigned short u) {
    return __uint_as_float(((unsigned)u) << 16);
}
__device__ __forceinline__ float gelu_f(float v) {
    return 0.5f * v * (1.f + erff(v * 0.70710678118654752f));
}
__device__ __forceinline__ void atomicMaxF(float* addr, float v) {
    if (v >= 0.f) atomicMax((int*)addr, __float_as_int(v));
    else          atomicMin((unsigned int*)addr, __float_as_uint(v));
}
// async global->LDS, 16B per lane; LDS dest = base + lane*16 (wave-linear)
__device__ __forceinline__ void gl2lds16(const uint4* g, uint4* l) {
    __builtin_amdgcn_global_load_lds(
        (const __attribute__((address_space(1))) void*)g,
        (__attribute__((address_space(3))) void*)l, 16, 0, 0);
}

// ---------------- edge partition by kg (stable, deterministic) ----------------
__global__ void part_count(const int* __restrict__ kg, int* __restrict__ bcnt) {
    int base = blockIdx.x * 1024;
    __shared__ int wc[4];
    int t = threadIdx.x, wave = t >> 6, lane = t & 63;
    int cnt = 0;
    #pragma unroll
    for (int s = 0; s < 4; ++s) {
        int j = base + s * 256 + t;
        int is0 = (j < NE && kg[j] == 0) ? 1 : 0;
        unsigned long long m = __ballot(is0);
        if (lane == 0) cnt += __popcll(m);
    }
    if (lane == 0) wc[wave] = cnt;
    __syncthreads();
    if (t == 0) bcnt[blockIdx.x] = wc[0] + wc[1] + wc[2] + wc[3];
}

__global__ void part_scan(const int* __restrict__ bcnt, int* __restrict__ bofs,
                          int* __restrict__ meta, int n) {
    if (threadIdx.x == 0 && blockIdx.x == 0) {
        int run = 0;
        for (int i = 0; i < n; ++i) { bofs[i] = run; run += bcnt[i]; }
        meta[0] = run;
    }
}

__global__ void part_scatter(const int* __restrict__ kg, const int* __restrict__ bofs,
                             const int* __restrict__ meta, int* __restrict__ perm) {
    int base = blockIdx.x * 1024;
    int c0 = meta[0];
    __shared__ int wz[4];
    int t = threadIdx.x, wave = t >> 6, lane = t & 63;
    int zrun = bofs[blockIdx.x];
    for (int s = 0; s < 4; ++s) {
        int j = base + s * 256 + t;
        int valid = j < NE;
        int is0 = (valid && kg[j] == 0) ? 1 : 0;
        unsigned long long m = __ballot(is0);
        int zb = __popcll(m & ((1ull << lane) - 1ull));
        if (lane == 0) wz[wave] = __popcll(m);
        __syncthreads();
        int wbefore = 0;
        for (int w = 0; w < wave; ++w) wbefore += wz[w];
        int zeros_before = zrun + wbefore + zb;
        if (valid) {
            int pos = is0 ? zeros_before : (c0 + (j - zeros_before));
            perm[pos] = j;
        }
        int stepz = wz[0] + wz[1] + wz[2] + wz[3];
        __syncthreads();
        zrun += stepz;
    }
}

// ---------------- prep kernels ----------------
__global__ void cast_x_kernel(const float* __restrict__ x, float* __restrict__ h, int n4) {
    for (int i = blockIdx.x * blockDim.x + threadIdx.x; i < n4; i += gridDim.x * blockDim.x)
        ((float4*)h)[i] = ((const float4*)x)[i];
}

__global__ void f2b_vec_kernel(const float* __restrict__ in, ushort* __restrict__ out, long n4) {
    long i0 = (long)blockIdx.x * blockDim.x + threadIdx.x;
    long stride = (long)gridDim.x * blockDim.x;
    for (long i = i0; i < n4; i += stride) {
        float4 v = ((const float4*)in)[i];
        ushort4 o;
        o.x = f2b(v.x); o.y = f2b(v.y); o.z = f2b(v.z); o.w = f2b(v.w);
        ((ushort4*)out)[i] = o;
    }
}

// out[s][o][d] = bf16(in[s][d][o]), dout = 256, din = 1<<shift
__global__ void transpose_w_kernel(const float* __restrict__ in, ushort* __restrict__ out,
                                   int shift, long total) {
    long i0 = (long)blockIdx.x * blockDim.x + threadIdx.x;
    long stride = (long)gridDim.x * blockDim.x;
    long dmask = ((long)1 << shift) - 1;
    for (long i = i0; i < total; i += stride) {
        long d = i & dmask;
        long rest = i >> shift;
        long o = rest & 255;
        long s = rest >> 8;
        out[i] = f2b(in[((s << shift) + d) * 256 + o]);
    }
}

__global__ void fill_kernel(float* __restrict__ p, float v, int n) {
    for (int i = blockIdx.x * blockDim.x + threadIdx.x; i < n; i += gridDim.x * blockDim.x)
        p[i] = v;
}

// ---------------- layernorm ----------------
__global__ __launch_bounds__(64) void ln_kernel(const float* __restrict__ h,
        const float* __restrict__ g, const float* __restrict__ b, bf16* __restrict__ hn) {
    int n = blockIdx.x, t = threadIdx.x;
    float4 v = ((const float4*)(h + (size_t)n * DD))[t];
    float s  = v.x + v.y + v.z + v.w;
    float s2 = v.x * v.x + v.y * v.y + v.z * v.z + v.w * v.w;
    #pragma unroll
    for (int off = 32; off; off >>= 1) {
        s  += __shfl_down(s, off);
        s2 += __shfl_down(s2, off);
    }
    s = __shfl(s, 0); s2 = __shfl(s2, 0);
    float mu  = s * (1.f / DD);
    float var = s2 * (1.f / DD) - mu * mu;
    float rs  = rsqrtf(var + 1e-5f);
    float vv[4] = {v.x, v.y, v.z, v.w};
    ushort4 pk;
    unsigned short* pku = (unsigned short*)&pk;
    #pragma unroll
    for (int j = 0; j < 4; ++j) {
        int c = t * 4 + j;
        pku[j] = f2b((vv[j] - mu) * rs * g[c] + b[c]);
    }
    ((ushort4*)(hn + (size_t)n * DD))[t] = pk;
}

// ---------------- qn: node-level q for BOTH branches: qn[br][node][ch] ----------------
__global__ __launch_bounds__(512) void qn_mfma(
        const bf16* __restrict__ hn, const ushort* __restrict__ WqT,
        const float* __restrict__ bq, ushort* __restrict__ qn) {
    __shared__ uint4 xh[64 * 32];   // 64 rows x 512B, xor-swizzled 16B slots
    __shared__ float bqs[2][256];
    int t = threadIdx.x;
    int n0 = blockIdx.x * 64;
    int wave = t >> 6, lane = t & 63;
    if (t < 256) { bqs[0][t] = bq[t]; bqs[1][t] = bq[256 + t]; }
    const uint4* hn4 = (const uint4*)hn;
    #pragma unroll
    for (int j = 0; j < 4; ++j) {
        int pr = wave * 4 + j;                 // pair of rows 2pr, 2pr+1
        int r2 = pr * 2 + (lane >> 5);
        int node = n0 + r2; if (node >= NN) node = NN - 1;
        int s = lane & 31;
        gl2lds16(hn4 + (size_t)node * 32 + (s ^ (r2 & 7)), &xh[pr * 64]);
    }
    __syncthreads();
    int lr = lane & 15, lg = lane >> 4;
    f32x4 acc[2][2][4];
    #pragma unroll
    for (int b = 0; b < 2; ++b)
        #pragma unroll
        for (int m = 0; m < 2; ++m)
            #pragma unroll
            for (int n = 0; n < 4; ++n) acc[b][m][n] = (f32x4){0.f, 0.f, 0.f, 0.f};
    const char* xhb = (const char*)xh;
    const ushort* qr0 = WqT + (size_t)(wave * 32 + lr) * 256 + lg * 8;
    const ushort* qr1 = WqT + (size_t)(wave * 32 + 16 + lr) * 256 + lg * 8;
    #pragma unroll
    for (int kk = 0; kk < 8; ++kk) {
        bf16x8 a00 = *(const bf16x8*)(qr0 + kk * 32);
        bf16x8 a01 = *(const bf16x8*)(qr1 + kk * 32);
        bf16x8 a10 = *(const bf16x8*)(qr0 + 65536 + kk * 32);
        bf16x8 a11 = *(const bf16x8*)(qr1 + 65536 + kk * 32);
        bf16x8 bfr[4];
        #pragma unroll
        for (int n = 0; n < 4; ++n) {
            int r = n * 16 + lr;
            bfr[n] = *(const bf16x8*)(xhb + r * 512 + (((kk * 4 + lg) ^ (r & 7)) << 4));
        }
        #pragma unroll
        for (int n = 0; n < 4; ++n) {
            acc[0][0][n] = __builtin_amdgcn_mfma_f32_16x16x32_bf16(a00, bfr[n], acc[0][0][n], 0, 0, 0);
            acc[0][1][n] = __builtin_amdgcn_mfma_f32_16x16x32_bf16(a01, bfr[n], acc[0][1][n], 0, 0, 0);
            acc[1][0][n] = __builtin_amdgcn_mfma_f32_16x16x32_bf16(a10, bfr[n], acc[1][0][n], 0, 0, 0);
            acc[1][1][n] = __builtin_amdgcn_mfma_f32_16x16x32_bf16(a11, bfr[n], acc[1][1][n], 0, 0, 0);
        }
    }
    #pragma unroll
    for (int n = 0; n < 4; ++n) {
        int e = n * 16 + lr;
        int node = n0 + e;
        if (node < NN) {
            #pragma unroll
            for (int br = 0; br < 2; ++br)
                #pragma unroll
                for (int m = 0; m < 2; ++m) {
                    int ob = wave * 32 + m * 16 + lg * 4;
                    f32x4 a = acc[br][m][n];
                    ushort4 pk;
                    unsigned short* pu = (unsigned short*)&pk;
                    #pragma unroll
                    for (int r = 0; r < 4; ++r) pu[r] = f2b(a[r] + bqs[br][ob + r]);
                    *(ushort4*)(qn + ((size_t)br * NN + node) * 256 + ob) = pk;
                }
        }
    }
}

// ---------------- transfer (+fused k +fused att): kg_src-homogeneous tiles ----------------
template<int RELB>
__global__ __launch_bounds__(512) void transfer_mfma(
        const bf16* __restrict__ hn, const float* __restrict__ rel,
        const ushort* __restrict__ relb,
        const int* __restrict__ src, const int* __restrict__ dst,
        const int* __restrict__ kgd,
        const int* __restrict__ perm, const int* __restrict__ meta,
        const ushort* __restrict__ WtT, const float* __restrict__ bt,
        const ushort* __restrict__ WkT, const float* __restrict__ bk,
        const ushort* __restrict__ qn, const float* __restrict__ beta,
        bf16* __restrict__ xjt, float* __restrict__ att) {
    __shared__ uint4 xh[64 * 32];   // hn halves; later holds xjt tile
    __shared__ uint4 xr[64 * 32];   // rel halves
    __shared__ float bts[256], bks[256];
    __shared__ float patt[8][64];
    __shared__ int sge[64], ssrc[64], sdst[64], sgd[64], sval[64];
    int t = threadIdx.x;
    int c0 = meta[0];
    int tiles0 = (c0 + 63) >> 6;
    int tiles1 = (NE - c0 + 63) >> 6;
    int bid = blockIdx.x;
    if (bid >= tiles0 + tiles1) return;
    int kgt, start, end;
    if (bid < tiles0) { kgt = 0; start = bid * 64; end = c0; }
    else              { kgt = 1; start = c0 + (bid - tiles0) * 64; end = NE; }
    int wave = t >> 6, lane = t & 63;
    if (t < 64) {
        int pos = start + t;
        int v = pos < end;
        int ge = perm[v ? pos : end - 1];
        sge[t] = ge; sval[t] = v; ssrc[t] = src[ge]; sdst[t] = dst[ge]; sgd[t] = kgd[ge];
    } else if (t >= 256) {
        int c = t & 255;
        bts[c] = bt[kgt * 256 + c];
        bks[c] = bk[kgt * 256 + c];
    }
    __syncthreads();
    const uint4* hn4 = (const uint4*)hn;
    #pragma unroll
    for (int j = 0; j < 4; ++j) {
        int pr = wave * 4 + j;
        int r2 = pr * 2 + (lane >> 5);
        int s = lane & 31;
        gl2lds16(hn4 + (size_t)ssrc[r2] * 32 + (s ^ (r2 & 7)), &xh[pr * 64]);
    }
    if (RELB) {
        const uint4* rb4 = (const uint4*)relb;
        #pragma unroll
        for (int j = 0; j < 4; ++j) {
            int pr = wave * 4 + j;
            int r2 = pr * 2 + (lane >> 5);
            int s = lane & 31;
            gl2lds16(rb4 + (size_t)sge[r2] * 32 + (s ^ (r2 & 7)), &xr[pr * 64]);
        }
    } else {
        #pragma unroll
        for (int i = 0; i < 8; ++i) {
            int r = i * 8 + wave;
            float4 f = ((const float4*)(rel + (size_t)sge[r] * 256))[lane];
            ushort4 o;
            o.x = f2b(f.x); o.y = f2b(f.y); o.z = f2b(f.z); o.w = f2b(f.w);
            int s = lane >> 1;
            char* bp = (char*)&xr[r * 32] + (((s ^ (r & 7)) << 4) | ((lane & 1) << 3));
            *(ushort4*)bp = o;
        }
    }
    __syncthreads();
    int lr = lane & 15, lg = lane >> 4;
    f32x4 acc[2][4];
    #pragma unroll
    for (int m = 0; m < 2; ++m)
        #pragma unroll
        for (int n = 0; n < 4; ++n) acc[m][n] = (f32x4){0.f, 0.f, 0.f, 0.f};
    const char* xhb = (const char*)xh;
    const char* xrb = (const char*)xr;
    const ushort* wb = WtT + (size_t)kgt * 131072;
    const ushort* wrow0 = wb + (size_t)(wave * 32 + lr) * 512 + lg * 8;
    const ushort* wrow1 = wb + (size_t)(wave * 32 + 16 + lr) * 512 + lg * 8;
    bf16x8 aX[2], aY[2];
    aX[0] = *(const bf16x8*)wrow0;
    aX[1] = *(const bf16x8*)wrow1;
    #pragma unroll 1
    for (int kk = 0; kk < 16; kk += 2) {
        aY[0] = *(const bf16x8*)(wrow0 + (kk + 1) * 32);
        aY[1] = *(const bf16x8*)(wrow1 + (kk + 1) * 32);
        {
            const char* sb = (kk & 8) ? xrb : xhb;
            int ks = (kk & 7) * 4 + lg;
            bf16x8 bfr[4];
            #pragma unroll
            for (int n = 0; n < 4; ++n) {
                int r = n * 16 + lr;
                bfr[n] = *(const bf16x8*)(sb + r * 512 + ((ks ^ (r & 7)) << 4));
            }
            #pragma unroll
            for (int m = 0; m < 2; ++m)
                #pragma unroll
                for (int n = 0; n < 4; ++n)
                    acc[m][n] = __builtin_amdgcn_mfma_f32_16x16x32_bf16(aX[m], bfr[n], acc[m][n], 0, 0, 0);
        }
        {
            int kn = (kk + 2 < 16) ? kk + 2 : 15;
            aX[0] = *(const bf16x8*)(wrow0 + kn * 32);
            aX[1] = *(const bf16x8*)(wrow1 + kn * 32);
        }
        {
            int k1 = kk + 1;
            const char* sb = (k1 & 8) ? xrb : xhb;
            int ks = (k1 & 7) * 4 + lg;
            bf16x8 bfr[4];
            #pragma unroll
            for (int n = 0; n < 4; ++n) {
                int r = n * 16 + lr;
                bfr[n] = *(const bf16x8*)(sb + r * 512 + ((ks ^ (r & 7)) << 4));
            }
            #pragma unroll
            for (int m = 0; m < 2; ++m)
                #pragma unroll
                for (int n = 0; n < 4; ++n)
                    acc[m][n] = __builtin_amdgcn_mfma_f32_16x16x32_bf16(aY[m], bfr[n], acc[m][n], 0, 0, 0);
        }
    }
    __syncthreads();
    // epilogue: bias + gelu, pack bf16 into swizzled 512B rows in xh
    char* xob = (char*)xh;
    #pragma unroll
    for (int n = 0; n < 4; ++n) {
        int e = n * 16 + lr;
        #pragma unroll
        for (int m = 0; m < 2; ++m) {
            int ob = wave * 32 + m * 16 + lg * 4;
            f32x4 a = acc[m][n];
            ushort4 pk;
            unsigned short* pu = (unsigned short*)&pk;
            #pragma unroll
            for (int r = 0; r < 4; ++r)
                pu[r] = f2b(gelu_f(a[r] + bts[ob + r]));
            int bofs = ob * 2;
            int slot = ((bofs >> 4) ^ (e & 7));
            *(ushort4*)(xob + e * 512 + slot * 16 + (bofs & 15)) = pk;
        }
    }
    __syncthreads();
    // ---- fused k-pass: k = Wk[kg] @ xjt_tile (bias added during dot) ----
    f32x4 kc[2][4];
    #pragma unroll
    for (int m = 0; m < 2; ++m)
        #pragma unroll
        for (int n = 0; n < 4; ++n) kc[m][n] = (f32x4){0.f, 0.f, 0.f, 0.f};
    const ushort* kbw = WkT + (size_t)kgt * 65536;
    const ushort* kr0 = kbw + (size_t)(wave * 32 + lr) * 256 + lg * 8;
    const ushort* kr1 = kbw + (size_t)(wave * 32 + 16 + lr) * 256 + lg * 8;
    #pragma unroll
    for (int kk = 0; kk < 8; ++kk) {
        bf16x8 a0 = *(const bf16x8*)(kr0 + kk * 32);
        bf16x8 a1 = *(const bf16x8*)(kr1 + kk * 32);
        bf16x8 bfr[4];
        #pragma unroll
        for (int n = 0; n < 4; ++n) {
            int r = n * 16 + lr;
            bfr[n] = *(const bf16x8*)(xob + r * 512 + (((kk * 4 + lg) ^ (r & 7)) << 4));
        }
        #pragma unroll
        for (int n = 0; n < 4; ++n) {
            kc[0][n] = __builtin_amdgcn_mfma_f32_16x16x32_bf16(a0, bfr[n], kc[0][n], 0, 0, 0);
            kc[1][n] = __builtin_amdgcn_mfma_f32_16x16x32_bf16(a1, bfr[n], kc[1][n], 0, 0, 0);
        }
    }
    // ---- fused att: gather q from qn, lane-local dot, reduce ----
    float p[4];
    #pragma unroll
    for (int n = 0; n < 4; ++n) {
        int e = n * 16 + lr;
        size_t qb = ((size_t)sgd[e] * NN + sdst[e]) * 256;
        float s = 0.f;
        #pragma unroll
        for (int m = 0; m < 2; ++m) {
            int ob = wave * 32 + m * 16 + lg * 4;
            ushort4 qv = *(const ushort4*)(qn + qb + ob);
            f32x4 kcv = kc[m][n];
            s = fmaf(b2f_bits(qv.x), kcv[0] + bks[ob + 0], s);
            s = fmaf(b2f_bits(qv.y), kcv[1] + bks[ob + 1], s);
            s = fmaf(b2f_bits(qv.z), kcv[2] + bks[ob + 2], s);
            s = fmaf(b2f_bits(qv.w), kcv[3] + bks[ob + 3], s);
        }
        p[n] = s;
    }
    #pragma unroll
    for (int n = 0; n < 4; ++n) {
        p[n] += __shfl_xor(p[n], 16);
        p[n] += __shfl_xor(p[n], 32);
    }
    if (lane < 16) {
        #pragma unroll
        for (int n = 0; n < 4; ++n) patt[wave][n * 16 + lr] = p[n];
    }
    // xjt store from LDS (coalesced 16B)
    uint4* xjv = (uint4*)xjt;
    #pragma unroll
    for (int i = 0; i < 4; ++i) {
        int flat = i * 512 + t;
        int r = flat >> 5, c = flat & 31;
        if (sval[r])
            xjv[(size_t)sge[r] * 32 + c] = *(const uint4*)(xob + r * 512 + ((c ^ (r & 7)) << 4));
    }
    __syncthreads();
    if (t < 256) {
        int e = t & 63, h = t >> 6;
        if (sval[e]) {
            int ge = sge[e];
            att[(size_t)ge * 4 + h] = (patt[2 * h][e] + patt[2 * h + 1][e]) * beta[ge] * 0.125f;
        }
    }
}

// ---------------- softmax / aggregate ----------------
__global__ void segmax_kernel(const float* __restrict__ att, const int* __restrict__ dst,
                              float* __restrict__ m) {
    int i = blockIdx.x * blockDim.x + threadIdx.x;
    if (i >= NE * 4) return;
    int e = i >> 2, h = i & 3;
    atomicMaxF(m + (size_t)dst[e] * 4 + h, att[i]);
}

__global__ void expsum_kernel(float* __restrict__ att, const int* __restrict__ dst,
                              const float* __restrict__ m, float* __restrict__ denom) {
    int i = blockIdx.x * blockDim.x + threadIdx.x;
    if (i >= NE * 4) return;
    int e = i >> 2, h = i & 3;
    float v = expf(att[i] - m[(size_t)dst[e] * 4 + h]);
    att[i] = v;
    atomicAdd(denom + (size_t)dst[e] * 4 + h, v);
}

// aggr accumulates UNNORMALIZED sums; division happens in finalize
__global__ __launch_bounds__(256) void scatter_kernel(const float* __restrict__ ev,
        const bf16* __restrict__ xjt, const int* __restrict__ dst, float* __restrict__ aggr) {
    int e = blockIdx.x, t = threadIdx.x;
    int de = dst[e];
    int h = t >> 6;
    float a = ev[(size_t)e * 4 + h];
    atomicAdd(aggr + (size_t)de * DD + t, a * bf2f(xjt[(size_t)e * DD + t]));
}

__global__ void finalize_kernel(float* __restrict__ h, const float* __restrict__ aggr,
                                const float* __restrict__ denom, int n) {
    for (int i = blockIdx.x * blockDim.x + threadIdx.x; i < n; i += gridDim.x * blockDim.x) {
        int node = i >> 8, hh = (i >> 6) & 3;
        float d = denom[(size_t)node * 4 + hh] + 1e-16f;
        h[i] = h[i] + gelu_f(aggr[i] / d);
    }
}

extern "C" void kernel_launch(void* const* d_in, const int* in_sizes, int n_in,
                              void* d_out, int out_size, void* d_ws, size_t ws_size,
                              hipStream_t stream) {
    const float* x    = (const float*)d_in[0];
    const int*   ei   = (const int*)d_in[1];
    const int*   ekg  = (const int*)d_in[2];
    const float* beta = (const float*)d_in[3];
    const float* rel  = (const float*)d_in[4];
    const float* ln_g = (const float*)d_in[5];
    const float* ln_b = (const float*)d_in[6];
    const float* Wt   = (const float*)d_in[7];
    const float* bt   = (const float*)d_in[8];
    const float* Wq   = (const float*)d_in[9];
    const float* bq   = (const float*)d_in[10];
    const float* Wk   = (const float*)d_in[11];
    const float* bk   = (const float*)d_in[12];

    float* h = (float*)d_out;   // residual stream (f32) in d_out

    const int* srcp = ei;
    const int* dstp = ei + NE;
    const int* kgs  = ekg;
    const int* kgd  = ekg + NE;

    char* w = (char*)d_ws;
    float*  aggr  = (float*)w;  w += (size_t)NN * DD * 4;        // 51.2 MB
    float*  att   = (float*)w;  w += (size_t)NE * 4 * 4;         //  4.8 MB
    float*  m_buf = (float*)w;  w += (size_t)NN * 4 * 4;
    float*  denom = (float*)w;  w += (size_t)NN * 4 * 4;
    bf16*   hn    = (bf16*)w;   w += (size_t)NN * DD * 2;        // 25.6 MB
    bf16*   xjt   = (bf16*)w;   w += (size_t)NE * DD * 2;        // 153.6 MB
    ushort* qn    = (ushort*)w; w += (size_t)2 * NN * DD * 2;    // 51.2 MB
    ushort* WtT   = (ushort*)w; w += (size_t)4 * 256 * 512 * 2;  // 1 MB
    ushort* WqT   = (ushort*)w; w += (size_t)4 * 256 * 256 * 2;
    ushort* WkT   = (ushort*)w; w += (size_t)4 * 256 * 256 * 2;
    int* perm_src = (int*)w;    w += (size_t)NE * 4;             // 1.2 MB
    int* bcnt0    = (int*)w;    w += NCHUNK * 4;
    int* bofs0    = (int*)w;    w += NCHUNK * 4;
    int* meta0    = (int*)w;    w += 64;
    size_t used = (size_t)(w - (char*)d_ws);
    ushort* relb = (ushort*)w;
    int use_relb = (ws_size >= used + (size_t)NE * DD * 2) ? 1 : 0;

    // edge partition by kg_src (static across layers)
    part_count<<<NCHUNK, 256, 0, stream>>>(kgs, bcnt0);
    part_scan<<<1, 64, 0, stream>>>(bcnt0, bofs0, meta0, NCHUNK);
    part_scatter<<<NCHUNK, 256, 0, stream>>>(kgs, bofs0, meta0, perm_src);

    cast_x_kernel<<<2048, 256, 0, stream>>>(x, h, NN * DD / 4);
    if (use_relb)
        f2b_vec_kernel<<<2048, 256, 0, stream>>>(rel, relb, (long)NE * DD / 4);
    transpose_w_kernel<<<512, 256, 0, stream>>>(Wt, WtT, 9, (long)4 * 256 * 512);
    transpose_w_kernel<<<256, 256, 0, stream>>>(Wq, WqT, 8, (long)4 * 256 * 256);
    transpose_w_kernel<<<256, 256, 0, stream>>>(Wk, WkT, 8, (long)4 * 256 * 256);

    const int EBP = (NE + 126) / 64;   // max tiles over both kg halves
    const int QB  = (NN + 63) / 64;
    for (int l = 0; l < 2; ++l) {
        ln_kernel<<<NN, 64, 0, stream>>>(h, ln_g + l * DD, ln_b + l * DD, hn);
        qn_mfma<<<QB, 512, 0, stream>>>(hn, WqT + (size_t)l * 2 * 256 * 256, bq + l * 512, qn);
        if (use_relb)
            transfer_mfma<1><<<EBP, 512, 0, stream>>>(hn, rel, relb, srcp, dstp, kgd,
                    perm_src, meta0,
                    WtT + (size_t)l * 2 * 256 * 512, bt + l * 512,
                    WkT + (size_t)l * 2 * 256 * 256, bk + l * 512, qn, beta, xjt, att);
        else
            transfer_mfma<0><<<EBP, 512, 0, stream>>>(hn, rel, relb, srcp, dstp, kgd,
                    perm_src, meta0,
                    WtT + (size_t)l * 2 * 256 * 512, bt + l * 512,
                    WkT + (size_t)l * 2 * 256 * 256, bk + l * 512, qn, beta, xjt, att);
        fill_kernel<<<256, 256, 0, stream>>>(m_buf, -1e30f, NN * 4);
        fill_kernel<<<256, 256, 0, stream>>>(denom, 0.f, NN * 4);
        fill_kernel<<<2048, 256, 0, stream>>>(aggr, 0.f, NN * DD);
        segmax_kernel<<<(NE * 4 + 255) / 256, 256, 0, stream>>>(att, dstp, m_buf);
        expsum_kernel<<<(NE * 4 + 255) / 256, 256, 0, stream>>>(att, dstp, m_buf, denom);
        scatter_kernel<<<NE, 256, 0, stream>>>(att, xjt, dstp, aggr);
        finalize_kernel<<<2048, 256, 0, stream>>>(h, aggr, denom, NN * DD);
    }
}